// Round 16
// baseline (618.742 us; speedup 1.0000x reference)
//
#include <hip/hip_runtime.h>
#include <math.h>

// ---------------------------------------------------------------------------
// DCN_89859305767621  Round 16:
//  - gcn2 FUSED into tail (same 64-row blocking): phase0 gather(shB)+self(xgF)
//    -> Ts-as-Z f16; phase0b G2 MFMA -> Xs[44:172] directly. Deletes the 2nd
//    gcn_fused launch + shA round-trip (25.6MB W + 12.8MB R). Bit-identical
//    values to R15 (same f16 staging points, int64 deterministic sum).
//  - everything else frozen from R15 (passed at 3.9e-3, 566us).
// ---------------------------------------------------------------------------

typedef __attribute__((ext_vector_type(8))) _Float16 f16x8;
typedef __attribute__((ext_vector_type(4))) _Float16 f16x4;
typedef __attribute__((ext_vector_type(2))) _Float16 f16x2;
typedef __attribute__((ext_vector_type(4))) float f32x4;

__device__ __forceinline__ float leakyf(float v) { return v > 0.f ? v : 0.01f * v; }

#define MFMA16(a, b, c) __builtin_amdgcn_mfma_f32_16x16x32_f16((a), (b), (c), 0, 0, 0)
#define AGG_SCALE 1048576.0f   // 2^20
#define AGG_INV   9.5367431640625e-07f

// ---------------- CSR build ----------------
__global__ __launch_bounds__(256) void cnt_edge_kernel(const int* __restrict__ dst,
                                                       int* __restrict__ cnt, int E)
{
    int i = blockIdx.x * 256 + threadIdx.x;
    if (i < E) atomicAdd(&cnt[dst[i]], 1);
}

__global__ __launch_bounds__(256) void scan1_kernel(const int* __restrict__ cnt,
                                                    int* __restrict__ incl,
                                                    int* __restrict__ bsum, int N)
{
    __shared__ int s[256];
    int tid = threadIdx.x;
    int i = blockIdx.x * 256 + tid;
    s[tid] = (i < N) ? cnt[i] : 0;
    __syncthreads();
    #pragma unroll
    for (int off = 1; off < 256; off <<= 1) {
        int t = (tid >= off) ? s[tid - off] : 0;
        __syncthreads();
        s[tid] += t;
        __syncthreads();
    }
    if (i < N) incl[i] = s[tid];
    if (tid == 255) bsum[blockIdx.x] = s[255];
}

__global__ void scan2_kernel(int* __restrict__ bsum, int nb)   // 1 block, 64 threads
{
    int lane = threadIdx.x & 63;
    int run = 0;
    for (int base = 0; base < nb; base += 64) {
        int i = base + lane;
        int orig = (i < nb) ? bsum[i] : 0;
        int v = orig;
        #pragma unroll
        for (int off = 1; off < 64; off <<= 1) {
            int t = __shfl_up(v, off, 64);
            if (lane >= off) v += t;
        }
        if (i < nb) bsum[i] = run + v - orig;
        run += __shfl(v, 63, 64);
    }
}

// row_ptr/cursor + dis = rsqrt(deg+1)
__global__ __launch_bounds__(256) void scan3_kernel(const int* __restrict__ incl,
                                                    const int* __restrict__ cnt,
                                                    const int* __restrict__ bsum,
                                                    int* __restrict__ row_ptr,
                                                    int* __restrict__ cursor,
                                                    float* __restrict__ dis, int N)
{
    int i = blockIdx.x * 256 + threadIdx.x;
    if (i < N) {
        int v = incl[i] - cnt[i] + bsum[i >> 8];
        row_ptr[i] = v;
        cursor[i] = v;
        dis[i] = rsqrtf((float)cnt[i] + 1.0f);
    }
}

// fill CSR adjacency with fused edge coefficient: colcf[p] = {src, dis_s*dis_d}
__global__ __launch_bounds__(256) void fill_kernel(const int* __restrict__ src,
                                                   const int* __restrict__ dst,
                                                   const float* __restrict__ dis,
                                                   int* __restrict__ cursor,
                                                   int2* __restrict__ colcf, int E)
{
    int e = blockIdx.x * 256 + threadIdx.x;
    if (e < E) {
        int s = src[e], d = dst[e];
        int p = atomicAdd(&cursor[d], 1);
        colcf[p] = make_int2(s, __float_as_int(dis[s] * dis[d]));
    }
}

// ---------------- weight prep: all 6 fp16 fragment planes + cvec, 1 launch --
__global__ __launch_bounds__(256) void wprep_kernel(
    const float* __restrict__ gcn1_W, const float* __restrict__ gcn2_W,
    const float* __restrict__ dnn_W1, const float* __restrict__ dnn_W2,
    const float* __restrict__ pred_W1,
    const float* __restrict__ cb, const float* __restrict__ cw,
    _Float16* __restrict__ G1f, _Float16* __restrict__ G2f,
    _Float16* __restrict__ W1f, _Float16* __restrict__ W2f,
    _Float16* __restrict__ Paf, _Float16* __restrict__ Pbf,
    float* __restrict__ cvec)
{
    int b = blockIdx.x;
    if (b == 704) {
        int col = threadIdx.x;
        if (col < 176) {
            float s = 0.f;
            if (col < 172)
                for (int k = 0; k < 172; ++k)
                    s += (cb[k] + cb[172 + k]) * pred_W1[(size_t)(172 + k) * 172 + col];
            cvec[col] = s;
        } else if (col == 176) {
            float c = 0.f;
            for (int k = 0; k < 172; ++k) c += cb[k] * cw[172 + k];
            cvec[176] = c;
        }
        return;
    }
    const float* W; _Float16* Wf; int K, Ncol, NT, base;
    if (b < 64)       { W = gcn1_W; Wf = G1f; K = 128; Ncol = 128; NT = 8;  base = 0;   }
    else if (b < 128) { W = gcn2_W; Wf = G2f; K = 128; Ncol = 128; NT = 8;  base = 64;  }
    else if (b < 272) { W = dnn_W1; Wf = W1f; K = 172; Ncol = 172; NT = 12; base = 128; }
    else if (b < 416) { W = dnn_W2; Wf = W2f; K = 172; Ncol = 172; NT = 12; base = 272; }
    else if (b < 560) { W = pred_W1; Wf = Paf; K = 172; Ncol = 172; NT = 12; base = 416; }
    else              { W = pred_W1 + (size_t)172 * 172; Wf = Pbf; K = 172; Ncol = 172; NT = 12; base = 560; }
    int idx = (b - base) * 256 + threadIdx.x;
    int e = idx & 7;
    int lane = (idx >> 3) & 63;
    int ct = idx >> 9;
    int t = ct % NT, c = ct / NT;
    int col = t * 16 + (lane & 15);
    int k = c * 32 + (lane >> 4) * 8 + e;
    float x = (k < K && col < Ncol) ? W[(size_t)k * Ncol + col] : 0.f;
    Wf[idx] = (_Float16)x;
}

// ---------------- g0: embed -> [N,44]@[44,128]+b, leaky -> xgF f32 + sh f16
__global__ __launch_bounds__(256) void g0_kernel(
    const int* __restrict__ disc, const float* __restrict__ cont,
    const float* __restrict__ Wc, const float* __restrict__ bc,
    const float* __restrict__ W, const float* __restrict__ bias,
    float* __restrict__ xg, _Float16* __restrict__ sh, int N)
{
    constexpr int TM = 32, K = 44, RB = 8;
    __shared__ float Alds[TM][K];
    __shared__ float Wlds[K][128];
    const int tid = threadIdx.x, lane = tid & 63, wv = tid >> 6;
    const int row0 = blockIdx.x * TM;

    for (int idx = tid; idx < TM * 38; idx += 256) {
        int r = idx / 38, j = idx - r * 38;
        int row = row0 + r;
        if (j == 0) {
            float o = 0.f;
            if (row < N) {
                const int* dr = disc + (size_t)row * 38;
                int best = dr[0], bi = 0;
                #pragma unroll
                for (int q = 1; q < 7; ++q) { int v = dr[q]; if (v > best) { best = v; bi = q; } }
                o = (float)bi;
            }
            Alds[r][0] = o;
        } else if (j >= 7) {
            Alds[r][j - 6] = (row < N) ? (float)disc[(size_t)row * 38 + j] : 0.f;
        }
    }
    for (int idx = tid; idx < TM * 12; idx += 256) {
        int r = idx / 12, q = idx - r * 12;
        int t = q >> 2, ch = q & 3;
        int row = row0 + r;
        float s = 0.f;
        if (row < N) {
            s = bc[ch];
            const float* cr = cont + (size_t)row * 90 + t * 30;
            #pragma unroll
            for (int j = 0; j < 30; ++j) s += cr[j] * Wc[j * 4 + ch];
        }
        Alds[r][32 + t * 4 + ch] = s;
    }
    for (int idx = tid; idx < K * 32; idx += 256) {
        int k = idx >> 5, c4 = idx & 31;
        ((float4*)&Wlds[k][0])[c4] = ((const float4*)W)[idx];
    }
    __syncthreads();

    float acc[RB][2];
    float b0 = bias[lane], b1 = bias[lane + 64];
    #pragma unroll
    for (int r = 0; r < RB; ++r) { acc[r][0] = b0; acc[r][1] = b1; }

    for (int k = 0; k < K; ++k) {
        float w0 = Wlds[k][lane], w1 = Wlds[k][lane + 64];
        #pragma unroll
        for (int r = 0; r < RB; ++r) {
            float a = Alds[wv * RB + r][k];
            acc[r][0] += a * w0;
            acc[r][1] += a * w1;
        }
    }
    #pragma unroll
    for (int r = 0; r < RB; ++r) {
        int row = row0 + wv * RB + r;
        if (row < N) {
            float v0 = leakyf(acc[r][0]);
            float v1 = leakyf(acc[r][1]);
            xg[(size_t)row * 128 + lane]      = v0;
            xg[(size_t)row * 128 + lane + 64] = v1;
            sh[(size_t)row * 128 + lane]      = (_Float16)v0;
            sh[(size_t)row * 128 + lane + 64] = (_Float16)v1;
        }
    }
}

// ---------------- GCN layer 1: xio/shout = leaky(AGG(shin,xio) @ G + b) ----
__global__ __launch_bounds__(512, 4) void gcn_fused(
    const _Float16* __restrict__ shin, float* __restrict__ xio,
    const int2* __restrict__ colcf,
    const int* __restrict__ rowp, const int* __restrict__ rend,
    const float* __restrict__ dis, const _Float16* __restrict__ B,
    const float* __restrict__ bias, _Float16* __restrict__ shout, int N)
{
    __shared__ __attribute__((aligned(16))) _Float16 Xs[64][136];
    const int tid = threadIdx.x, lane = tid & 63, wv = tid >> 6;
    const int l15 = lane & 15, kq = lane >> 4;
    const int row0 = blockIdx.x * 64;
    const f16x2* S2 = (const f16x2*)shin;
    const float2* X2 = (const float2*)xio;

    // ---- phase 1: gather (f16 neighbors) + self-loop (f32), int64 sum
    #pragma unroll 1
    for (int rr = 0; rr < 8; ++rr) {
        const int r = (wv << 3) + rr;
        const int row = row0 + r;
        float ox = 0.f, oy = 0.f;
        if (row < N) {
            int i = rowp[row], en = rend[row];
            long long iax = 0, iay = 0;
            for (; i + 7 < en; i += 8) {
                int2 ee[8];
                f16x2 vv[8];
                #pragma unroll
                for (int u = 0; u < 8; ++u) ee[u] = colcf[i + u];
                #pragma unroll
                for (int u = 0; u < 8; ++u) vv[u] = S2[(size_t)ee[u].x * 64 + lane];
                #pragma unroll
                for (int u = 0; u < 8; ++u) {
                    float cf = __int_as_float(ee[u].y) * AGG_SCALE;
                    iax += __float2int_rn((float)vv[u].x * cf);
                    iay += __float2int_rn((float)vv[u].y * cf);
                }
            }
            for (; i < en; ++i) {
                int2 e = colcf[i];
                f16x2 v = S2[(size_t)e.x * 64 + lane];
                float cf = __int_as_float(e.y) * AGG_SCALE;
                iax += __float2int_rn((float)v.x * cf);
                iay += __float2int_rn((float)v.y * cf);
            }
            float ax = (float)iax * AGG_INV;
            float ay = (float)iay * AGG_INV;
            float dn = dis[row];
            float2 sv = X2[(size_t)row * 64 + lane];
            float d2 = dn * dn;
            ox = ax + sv.x * d2;
            oy = ay + sv.y * d2;
        }
        f16x2 h = { (_Float16)ox, (_Float16)oy };
        *(f16x2*)&Xs[r][lane * 2] = h;
    }
    __syncthreads();

    // ---- phase 2: GEMM (wave = msub x half; 4 col-tiles per wave)
    const int msub = wv >> 1, half = wv & 1;
    f32x4 acc[4];
    #pragma unroll
    for (int t = 0; t < 4; ++t) acc[t] = (f32x4){0.f, 0.f, 0.f, 0.f};

    #pragma unroll
    for (int c = 0; c < 4; ++c) {
        f16x8 a = *(const f16x8*)&Xs[msub * 16 + l15][c * 32 + kq * 8];
        #pragma unroll
        for (int t = 0; t < 4; ++t) {
            int tg = half * 4 + t;
            f16x8 b = *(const f16x8*)(B + (((size_t)c * 8 + tg) * 64 + lane) * 8);
            acc[t] = MFMA16(a, b, acc[t]);
        }
    }

    #pragma unroll
    for (int t = 0; t < 4; ++t) {
        int col = (half * 4 + t) * 16 + l15;
        float bb = bias[col];
        #pragma unroll
        for (int r = 0; r < 4; ++r) {
            int row = row0 + msub * 16 + kq * 4 + r;
            if (row < N) {
                float v = leakyf(acc[t][r] + bb);
                xio[(size_t)row * 128 + col] = v;
                shout[(size_t)row * 128 + col] = (_Float16)v;
            }
        }
    }
}

// one pass: 6 K-chunks x 6 N-tiles per wave (cols half*96 + t*16 + l15)
__device__ __forceinline__ void gemm_pass6(
    const _Float16 (*X)[200], const _Float16* __restrict__ B,
    f32x4* acc, int msub, int half, int l15, int kq, int lane)
{
    #pragma unroll
    for (int t = 0; t < 6; ++t) acc[t] = (f32x4){0.f, 0.f, 0.f, 0.f};
    #pragma unroll
    for (int c = 0; c < 6; ++c) {
        f16x8 a = *(const f16x8*)&X[msub * 16 + l15][c * 32 + kq * 8];
        #pragma unroll
        for (int t = 0; t < 6; ++t) {
            f16x8 b = *(const f16x8*)(B + (((size_t)c * 12 + half * 6 + t) * 64 + lane) * 8);
            acc[t] = MFMA16(a, b, acc[t]);
        }
    }
}

// ---- fused tail: gcn2 + dnn1 + dnn2 + pred1(a,b) + cross + pred2 + sigmoid
__global__ __launch_bounds__(512, 3) void tail_kernel(
    const int* __restrict__ disc, const float* __restrict__ cont,
    const float* __restrict__ Wc, const float* __restrict__ bc,
    const _Float16* __restrict__ shB, const float* __restrict__ xgF,
    const int2* __restrict__ colcf,
    const int* __restrict__ rowp, const int* __restrict__ rend,
    const float* __restrict__ dis,
    const _Float16* __restrict__ G2, const float* __restrict__ g2b,
    const _Float16* __restrict__ W1, const float* __restrict__ b1,
    const _Float16* __restrict__ W2, const float* __restrict__ b2,
    const _Float16* __restrict__ Pa, const _Float16* __restrict__ Pb,
    const float* __restrict__ pb1,
    const float* __restrict__ cw, const float* __restrict__ cvec,
    const float* __restrict__ pw2, const float* __restrict__ pb2,
    float* __restrict__ out, int N)
{
    __shared__ __attribute__((aligned(16))) _Float16 Xs[64][200];
    __shared__ __attribute__((aligned(16))) _Float16 Ts[64][200];
    __shared__ float als[64];
    __shared__ float partial[64][2];
    const int tid = threadIdx.x, lane = tid & 63, wv = tid >> 6;
    const int msub = wv >> 1, half = wv & 1, l15 = lane & 15, kq = lane >> 4;
    const int row0 = blockIdx.x * 64;

    // ---- phase 0: gcn2 gather (shB neighbors f16 + xgF self f32) -> Ts-as-Z
    {
        const f16x2* S2 = (const f16x2*)shB;
        const float2* X2 = (const float2*)xgF;
        #pragma unroll 1
        for (int rr = 0; rr < 8; ++rr) {
            const int r = (wv << 3) + rr;
            const int row = row0 + r;
            float ox = 0.f, oy = 0.f;
            if (row < N) {
                int i = rowp[row], en = rend[row];
                long long iax = 0, iay = 0;
                for (; i + 7 < en; i += 8) {
                    int2 ee[8];
                    f16x2 vv[8];
                    #pragma unroll
                    for (int u = 0; u < 8; ++u) ee[u] = colcf[i + u];
                    #pragma unroll
                    for (int u = 0; u < 8; ++u) vv[u] = S2[(size_t)ee[u].x * 64 + lane];
                    #pragma unroll
                    for (int u = 0; u < 8; ++u) {
                        float cf = __int_as_float(ee[u].y) * AGG_SCALE;
                        iax += __float2int_rn((float)vv[u].x * cf);
                        iay += __float2int_rn((float)vv[u].y * cf);
                    }
                }
                for (; i < en; ++i) {
                    int2 e = colcf[i];
                    f16x2 v = S2[(size_t)e.x * 64 + lane];
                    float cf = __int_as_float(e.y) * AGG_SCALE;
                    iax += __float2int_rn((float)v.x * cf);
                    iay += __float2int_rn((float)v.y * cf);
                }
                float ax = (float)iax * AGG_INV;
                float ay = (float)iay * AGG_INV;
                float dn = dis[row];
                float2 sv = X2[(size_t)row * 64 + lane];
                float d2 = dn * dn;
                ox = ax + sv.x * d2;
                oy = ay + sv.y * d2;
            }
            f16x2 h = { (_Float16)ox, (_Float16)oy };
            *(f16x2*)&Ts[r][lane * 2] = h;
        }
    }
    __syncthreads();

    // ---- phase 0b: G2 GEMM (K=128) from Ts -> Xs[44:172] (leaky+bias, f16)
    {
        f32x4 acc[4];
        #pragma unroll
        for (int t = 0; t < 4; ++t) acc[t] = (f32x4){0.f, 0.f, 0.f, 0.f};
        #pragma unroll
        for (int c = 0; c < 4; ++c) {
            f16x8 a = *(const f16x8*)&Ts[msub * 16 + l15][c * 32 + kq * 8];
            #pragma unroll
            for (int t = 0; t < 4; ++t) {
                int tg = half * 4 + t;
                f16x8 b = *(const f16x8*)(G2 + (((size_t)c * 8 + tg) * 64 + lane) * 8);
                acc[t] = MFMA16(a, b, acc[t]);
            }
        }
        #pragma unroll
        for (int t = 0; t < 4; ++t) {
            int col = (half * 4 + t) * 16 + l15;
            float bb = g2b[col];
            #pragma unroll
            for (int r = 0; r < 4; ++r) {
                int row = msub * 16 + kq * 4 + r;
                Xs[row][44 + col] = (_Float16)leakyf(acc[t][r] + bb);
            }
        }
    }
    __syncthreads();

    // ---- phase A: coalesced cont tile -> Ts-as-f32 [64][100]
    float* TsF = (float*)&Ts[0][0];
    for (int idx = tid; idx < 64 * 45; idx += 512) {
        int r = idx / 45, j2 = idx - r * 45;
        int row = row0 + r;
        float2 v = make_float2(0.f, 0.f);
        if (row < N) v = ((const float2*)(cont + (size_t)row * 90))[j2];
        TsF[r * 100 + j2 * 2]     = v.x;
        TsF[r * 100 + j2 * 2 + 1] = v.y;
    }
    __syncthreads();

    // ---- phase B: embed from LDS (same f32 order) -> Xs[0:44] + pad
    for (int idx = tid; idx < 64 * 44; idx += 512) {
        int r = idx / 44, j = idx - r * 44;
        int row = row0 + r;
        float v = 0.f;
        if (row < N) {
            if (j == 0) {
                const int* dr = disc + (size_t)row * 38;
                int best = dr[0], bi = 0;
                #pragma unroll
                for (int q = 1; q < 7; ++q) { int t = dr[q]; if (t > best) { best = t; bi = q; } }
                v = (float)bi;
            } else if (j < 32) {
                v = (float)disc[(size_t)row * 38 + j + 6];
            } else {
                int q = j - 32, t = q >> 2, ch = q & 3;
                float s = bc[ch];
                const float* crl = &TsF[r * 100 + t * 30];
                #pragma unroll
                for (int kk = 0; kk < 30; ++kk) s += crl[kk] * Wc[kk * 4 + ch];
                v = s;
            }
        }
        Xs[r][j] = (_Float16)v;
    }
    for (int idx = tid; idx < 64 * 28; idx += 512) {
        int r = idx / 28, j = idx - r * 28;
        Xs[r][172 + j] = (_Float16)0.f;
    }
    __syncthreads();

    // per-row cross scalars: xl2 = als*x0 + (b1c+b2c)
    {
        int row = tid >> 3, sub = tid & 7;
        float d1 = 0.f, d2 = 0.f;
        for (int col = sub; col < 172; col += 8) {
            float x = (float)Xs[row][col];
            d1 += x * cw[col];
            d2 += x * cw[172 + col];
        }
        #pragma unroll
        for (int off = 1; off < 8; off <<= 1) {
            d1 += __shfl_xor(d1, off, 64);
            d2 += __shfl_xor(d2, off, 64);
        }
        if (sub == 0) {
            float a1 = 1.f + d1;
            als[row] = a1 + a1 * d2 + cvec[176];
        }
    }
    __syncthreads();

    f32x4 accA[6], accB[6];

    // dnn1: Xs -> Ts
    gemm_pass6(Xs, W1, accA, msub, half, l15, kq, lane);
    __syncthreads();
    #pragma unroll
    for (int t = 0; t < 6; ++t) {
        int col = half * 96 + t * 16 + l15;
        #pragma unroll
        for (int r = 0; r < 4; ++r) {
            int row = msub * 16 + kq * 4 + r;
            float v = (col < 172) ? leakyf(accA[t][r] + b1[col]) : 0.f;
            Ts[row][col] = (_Float16)v;
        }
    }
    __syncthreads();
    // dnn2: Ts -> Ts (in place)
    gemm_pass6(Ts, W2, accA, msub, half, l15, kq, lane);
    __syncthreads();
    #pragma unroll
    for (int t = 0; t < 6; ++t) {
        int col = half * 96 + t * 16 + l15;
        #pragma unroll
        for (int r = 0; r < 4; ++r) {
            int row = msub * 16 + kq * 4 + r;
            float v = (col < 172) ? leakyf(accA[t][r] + b2[col]) : 0.f;
            Ts[row][col] = (_Float16)v;
        }
    }
    __syncthreads();

    // pred1: accA = xdeep@Pa (from Ts), accB = x0@Pb (from Xs)
    gemm_pass6(Ts, Pa, accA, msub, half, l15, kq, lane);
    gemm_pass6(Xs, Pb, accB, msub, half, l15, kq, lane);

    // epilogue: pre = accA + pb1 + als*accB + cvec -> leaky -> . pw2 -> sigmoid
    float part[4] = {0.f, 0.f, 0.f, 0.f};
    #pragma unroll
    for (int t = 0; t < 6; ++t) {
        int col = half * 96 + t * 16 + l15;
        if (col < 172) {
            float cv = cvec[col] + pb1[col], w2v = pw2[col];
            #pragma unroll
            for (int r = 0; r < 4; ++r) {
                int row = msub * 16 + kq * 4 + r;
                float pre = accA[t][r] + als[row] * accB[t][r] + cv;
                part[r] += leakyf(pre) * w2v;
            }
        }
    }
    #pragma unroll
    for (int r = 0; r < 4; ++r) {
        #pragma unroll
        for (int off = 1; off < 16; off <<= 1)
            part[r] += __shfl_xor(part[r], off, 64);
    }
    if (l15 == 0) {
        #pragma unroll
        for (int r = 0; r < 4; ++r)
            partial[msub * 16 + kq * 4 + r][half] = part[r];
    }
    __syncthreads();
    if (tid < 64) {
        int grow = row0 + tid;
        if (grow < N) {
            float s = partial[tid][0] + partial[tid][1] + pb2[0];
            out[grow] = 1.f / (1.f + expf(-s));
        }
    }
}

extern "C" void kernel_launch(void* const* d_in, const int* in_sizes, int n_in,
                              void* d_out, int out_size, void* d_ws, size_t ws_size,
                              hipStream_t stream)
{
    const int*   disc    = (const int*)d_in[0];
    const float* cont    = (const float*)d_in[1];
    const int*   eidx    = (const int*)d_in[2];
    const float* emb_W   = (const float*)d_in[5];
    const float* emb_b   = (const float*)d_in[6];
    const float* g0_W    = (const float*)d_in[7];
    const float* g0_b    = (const float*)d_in[8];
    const float* gcn1_W  = (const float*)d_in[9];
    const float* gcn1_b  = (const float*)d_in[10];
    const float* gcn2_W  = (const float*)d_in[11];
    const float* gcn2_b  = (const float*)d_in[12];
    const float* dnn_W1  = (const float*)d_in[13];
    const float* dnn_b1  = (const float*)d_in[14];
    const float* dnn_W2  = (const float*)d_in[15];
    const float* dnn_b2  = (const float*)d_in[16];
    const float* cross_w = (const float*)d_in[17];
    const float* cross_b = (const float*)d_in[18];
    const float* pred_W1 = (const float*)d_in[19];
    const float* pred_b1 = (const float*)d_in[20];
    const float* pred_W2 = (const float*)d_in[21];
    const float* pred_b2 = (const float*)d_in[22];

    const int N = in_sizes[0] / 38;
    const int E = in_sizes[2] / 2;
    const int* src = eidx;
    const int* dst = eidx + E;

    // ---- workspace (~117.7 MB — same layout as proven R15) ----
    float* xgF     = (float*)d_ws;                        // [N,128] f32 (in-place)
    _Float16* shA  = (_Float16*)(xgF + (size_t)128 * N);  // [N,128] f16 (g0 shadow)
    _Float16* shB  = shA + (size_t)128 * N;               // [N,128] f16 (gcn1 shadow)
    float* dis  = (float*)(shB + (size_t)128 * N);        // [N]
    int* cnt    = (int*)(dis + N);                        // [N]
    int* rowp   = cnt + N;                                // [N]
    int* curs   = rowp + N;                               // [N]
    int* bsum   = curs + N;                               // [512]
    int2* colcf = (int2*)(((size_t)(bsum + 512) + 15) & ~(size_t)15);  // [E]
    _Float16* wf = (_Float16*)(colcf + E);
    _Float16* G1f = wf;              // 4*8*512   = 16384
    _Float16* G2f = G1f + 16384;
    _Float16* W1f = G2f + 16384;     // 6*12*512  = 36864
    _Float16* W2f = W1f + 36864;
    _Float16* Paf = W2f + 36864;
    _Float16* Pbf = Paf + 36864;
    float* cvec   = (float*)(Pbf + 36864);                // [192]

    auto cdiv = [](int a, int b) { return (a + b - 1) / b; };
    const int nb = cdiv(N, 256);

    // weight prep: all planes + cvec in ONE launch
    wprep_kernel<<<705, 256, 0, stream>>>(
        gcn1_W, gcn2_W, dnn_W1, dnn_W2, pred_W1, cross_b, cross_w,
        G1f, G2f, W1f, W2f, Paf, Pbf, cvec);

    // CSR build (+ per-edge coeff)
    hipMemsetAsync(cnt, 0, (size_t)N * sizeof(int), stream);
    cnt_edge_kernel<<<cdiv(E, 256), 256, 0, stream>>>(dst, cnt, E);
    scan1_kernel<<<nb, 256, 0, stream>>>(cnt, curs, bsum, N);
    scan2_kernel<<<1, 64, 0, stream>>>(bsum, nb);
    scan3_kernel<<<nb, 256, 0, stream>>>(curs, cnt, bsum, rowp, curs, dis, N);
    fill_kernel<<<cdiv(E, 256), 256, 0, stream>>>(src, dst, dis, curs, colcf, E);

    // g0 -> xgF (f32) + shA (f16)
    g0_kernel<<<cdiv(N, 32), 256, 0, stream>>>(disc, cont, emb_W, emb_b, g0_W, g0_b,
                                               xgF, shA, N);

    // GCN L1: gather shA, self xgF, write xgF (in-place) + shB
    gcn_fused<<<cdiv(N, 64), 512, 0, stream>>>(shA, xgF, colcf, rowp, curs, dis,
                                               G1f, gcn1_b, shB, N);

    // fused tail (gcn2 + dnn + cross + pred) -> out
    tail_kernel<<<cdiv(N, 64), 512, 0, stream>>>(
        disc, cont, emb_W, emb_b, shB, xgF, colcf, rowp, curs, dis,
        G2f, gcn2_b, W1f, dnn_b1, W2f, dnn_b2, Paf, Pbf, pred_b1,
        cross_w, cvec, pred_W2, pred_b2, (float*)d_out, N);
}

// Round 17
// 570.107 us; speedup vs baseline: 1.0853x; 1.0853x over previous
//
#include <hip/hip_runtime.h>
#include <math.h>

// ---------------------------------------------------------------------------
// DCN_89859305767621  Round 17 = Round 15 revert (best proven: 566us, 3.9e-3)
//  R16's gcn2-into-tail fusion REGRESSED (618us): gather lost occupancy
//  (3 blocks/CU @52KB LDS vs 4 @17KB) and cross-block overlap. Reverted.
//  - f16 shadow gather (halved gather bytes), f32 self-loop, int64
//    deterministic agg sum, fused tail with accA/accB in regs, 11 launches.
// ---------------------------------------------------------------------------

typedef __attribute__((ext_vector_type(8))) _Float16 f16x8;
typedef __attribute__((ext_vector_type(4))) _Float16 f16x4;
typedef __attribute__((ext_vector_type(2))) _Float16 f16x2;
typedef __attribute__((ext_vector_type(4))) float f32x4;

__device__ __forceinline__ float leakyf(float v) { return v > 0.f ? v : 0.01f * v; }

#define MFMA16(a, b, c) __builtin_amdgcn_mfma_f32_16x16x32_f16((a), (b), (c), 0, 0, 0)
#define AGG_SCALE 1048576.0f   // 2^20
#define AGG_INV   9.5367431640625e-07f

// ---------------- CSR build ----------------
__global__ __launch_bounds__(256) void cnt_edge_kernel(const int* __restrict__ dst,
                                                       int* __restrict__ cnt, int E)
{
    int i = blockIdx.x * 256 + threadIdx.x;
    if (i < E) atomicAdd(&cnt[dst[i]], 1);
}

__global__ __launch_bounds__(256) void scan1_kernel(const int* __restrict__ cnt,
                                                    int* __restrict__ incl,
                                                    int* __restrict__ bsum, int N)
{
    __shared__ int s[256];
    int tid = threadIdx.x;
    int i = blockIdx.x * 256 + tid;
    s[tid] = (i < N) ? cnt[i] : 0;
    __syncthreads();
    #pragma unroll
    for (int off = 1; off < 256; off <<= 1) {
        int t = (tid >= off) ? s[tid - off] : 0;
        __syncthreads();
        s[tid] += t;
        __syncthreads();
    }
    if (i < N) incl[i] = s[tid];
    if (tid == 255) bsum[blockIdx.x] = s[255];
}

__global__ void scan2_kernel(int* __restrict__ bsum, int nb)   // 1 block, 64 threads
{
    int lane = threadIdx.x & 63;
    int run = 0;
    for (int base = 0; base < nb; base += 64) {
        int i = base + lane;
        int orig = (i < nb) ? bsum[i] : 0;
        int v = orig;
        #pragma unroll
        for (int off = 1; off < 64; off <<= 1) {
            int t = __shfl_up(v, off, 64);
            if (lane >= off) v += t;
        }
        if (i < nb) bsum[i] = run + v - orig;
        run += __shfl(v, 63, 64);
    }
}

// row_ptr/cursor + dis = rsqrt(deg+1)
__global__ __launch_bounds__(256) void scan3_kernel(const int* __restrict__ incl,
                                                    const int* __restrict__ cnt,
                                                    const int* __restrict__ bsum,
                                                    int* __restrict__ row_ptr,
                                                    int* __restrict__ cursor,
                                                    float* __restrict__ dis, int N)
{
    int i = blockIdx.x * 256 + threadIdx.x;
    if (i < N) {
        int v = incl[i] - cnt[i] + bsum[i >> 8];
        row_ptr[i] = v;
        cursor[i] = v;
        dis[i] = rsqrtf((float)cnt[i] + 1.0f);
    }
}

// fill CSR adjacency with fused edge coefficient: colcf[p] = {src, dis_s*dis_d}
__global__ __launch_bounds__(256) void fill_kernel(const int* __restrict__ src,
                                                   const int* __restrict__ dst,
                                                   const float* __restrict__ dis,
                                                   int* __restrict__ cursor,
                                                   int2* __restrict__ colcf, int E)
{
    int e = blockIdx.x * 256 + threadIdx.x;
    if (e < E) {
        int s = src[e], d = dst[e];
        int p = atomicAdd(&cursor[d], 1);
        colcf[p] = make_int2(s, __float_as_int(dis[s] * dis[d]));
    }
}

// ---------------- weight prep: all 6 fp16 fragment planes + cvec, 1 launch --
__global__ __launch_bounds__(256) void wprep_kernel(
    const float* __restrict__ gcn1_W, const float* __restrict__ gcn2_W,
    const float* __restrict__ dnn_W1, const float* __restrict__ dnn_W2,
    const float* __restrict__ pred_W1,
    const float* __restrict__ cb, const float* __restrict__ cw,
    _Float16* __restrict__ G1f, _Float16* __restrict__ G2f,
    _Float16* __restrict__ W1f, _Float16* __restrict__ W2f,
    _Float16* __restrict__ Paf, _Float16* __restrict__ Pbf,
    float* __restrict__ cvec)
{
    int b = blockIdx.x;
    if (b == 704) {
        int col = threadIdx.x;
        if (col < 176) {
            float s = 0.f;
            if (col < 172)
                for (int k = 0; k < 172; ++k)
                    s += (cb[k] + cb[172 + k]) * pred_W1[(size_t)(172 + k) * 172 + col];
            cvec[col] = s;
        } else if (col == 176) {
            float c = 0.f;
            for (int k = 0; k < 172; ++k) c += cb[k] * cw[172 + k];
            cvec[176] = c;
        }
        return;
    }
    const float* W; _Float16* Wf; int K, Ncol, NT, base;
    if (b < 64)       { W = gcn1_W; Wf = G1f; K = 128; Ncol = 128; NT = 8;  base = 0;   }
    else if (b < 128) { W = gcn2_W; Wf = G2f; K = 128; Ncol = 128; NT = 8;  base = 64;  }
    else if (b < 272) { W = dnn_W1; Wf = W1f; K = 172; Ncol = 172; NT = 12; base = 128; }
    else if (b < 416) { W = dnn_W2; Wf = W2f; K = 172; Ncol = 172; NT = 12; base = 272; }
    else if (b < 560) { W = pred_W1; Wf = Paf; K = 172; Ncol = 172; NT = 12; base = 416; }
    else              { W = pred_W1 + (size_t)172 * 172; Wf = Pbf; K = 172; Ncol = 172; NT = 12; base = 560; }
    int idx = (b - base) * 256 + threadIdx.x;
    int e = idx & 7;
    int lane = (idx >> 3) & 63;
    int ct = idx >> 9;
    int t = ct % NT, c = ct / NT;
    int col = t * 16 + (lane & 15);
    int k = c * 32 + (lane >> 4) * 8 + e;
    float x = (k < K && col < Ncol) ? W[(size_t)k * Ncol + col] : 0.f;
    Wf[idx] = (_Float16)x;
}

// ---------------- g0: embed -> [N,44]@[44,128]+b, leaky -> xgF f32 + sh f16
__global__ __launch_bounds__(256) void g0_kernel(
    const int* __restrict__ disc, const float* __restrict__ cont,
    const float* __restrict__ Wc, const float* __restrict__ bc,
    const float* __restrict__ W, const float* __restrict__ bias,
    float* __restrict__ xg, _Float16* __restrict__ sh, int N)
{
    constexpr int TM = 32, K = 44, RB = 8;
    __shared__ float Alds[TM][K];
    __shared__ float Wlds[K][128];
    const int tid = threadIdx.x, lane = tid & 63, wv = tid >> 6;
    const int row0 = blockIdx.x * TM;

    for (int idx = tid; idx < TM * 38; idx += 256) {
        int r = idx / 38, j = idx - r * 38;
        int row = row0 + r;
        if (j == 0) {
            float o = 0.f;
            if (row < N) {
                const int* dr = disc + (size_t)row * 38;
                int best = dr[0], bi = 0;
                #pragma unroll
                for (int q = 1; q < 7; ++q) { int v = dr[q]; if (v > best) { best = v; bi = q; } }
                o = (float)bi;
            }
            Alds[r][0] = o;
        } else if (j >= 7) {
            Alds[r][j - 6] = (row < N) ? (float)disc[(size_t)row * 38 + j] : 0.f;
        }
    }
    for (int idx = tid; idx < TM * 12; idx += 256) {
        int r = idx / 12, q = idx - r * 12;
        int t = q >> 2, ch = q & 3;
        int row = row0 + r;
        float s = 0.f;
        if (row < N) {
            s = bc[ch];
            const float* cr = cont + (size_t)row * 90 + t * 30;
            #pragma unroll
            for (int j = 0; j < 30; ++j) s += cr[j] * Wc[j * 4 + ch];
        }
        Alds[r][32 + t * 4 + ch] = s;
    }
    for (int idx = tid; idx < K * 32; idx += 256) {
        int k = idx >> 5, c4 = idx & 31;
        ((float4*)&Wlds[k][0])[c4] = ((const float4*)W)[idx];
    }
    __syncthreads();

    float acc[RB][2];
    float b0 = bias[lane], b1 = bias[lane + 64];
    #pragma unroll
    for (int r = 0; r < RB; ++r) { acc[r][0] = b0; acc[r][1] = b1; }

    for (int k = 0; k < K; ++k) {
        float w0 = Wlds[k][lane], w1 = Wlds[k][lane + 64];
        #pragma unroll
        for (int r = 0; r < RB; ++r) {
            float a = Alds[wv * RB + r][k];
            acc[r][0] += a * w0;
            acc[r][1] += a * w1;
        }
    }
    #pragma unroll
    for (int r = 0; r < RB; ++r) {
        int row = row0 + wv * RB + r;
        if (row < N) {
            float v0 = leakyf(acc[r][0]);
            float v1 = leakyf(acc[r][1]);
            xg[(size_t)row * 128 + lane]      = v0;
            xg[(size_t)row * 128 + lane + 64] = v1;
            sh[(size_t)row * 128 + lane]      = (_Float16)v0;
            sh[(size_t)row * 128 + lane + 64] = (_Float16)v1;
        }
    }
}

// ---------------- fused GCN layer: out = leaky(AGG(x) @ G + b) -------------
// gather reads f16 shadow (half bytes); self-loop reads f32 xio (exact);
// f32 output written in-place to xio (skipped when write_f32=0);
// f16 shadow of the result written to shout.
__global__ __launch_bounds__(512, 4) void gcn_fused(
    const _Float16* __restrict__ shin, float* __restrict__ xio,
    const int2* __restrict__ colcf,
    const int* __restrict__ rowp, const int* __restrict__ rend,
    const float* __restrict__ dis, const _Float16* __restrict__ B,
    const float* __restrict__ bias, _Float16* __restrict__ shout,
    int write_f32, int N)
{
    __shared__ __attribute__((aligned(16))) _Float16 Xs[64][136];
    const int tid = threadIdx.x, lane = tid & 63, wv = tid >> 6;
    const int l15 = lane & 15, kq = lane >> 4;
    const int row0 = blockIdx.x * 64;
    const f16x2* S2 = (const f16x2*)shin;
    const float2* X2 = (const float2*)xio;

    // ---- phase 1: gather (f16 neighbors) + self-loop (f32), int64 sum
    #pragma unroll 1
    for (int rr = 0; rr < 8; ++rr) {
        const int r = (wv << 3) + rr;
        const int row = row0 + r;
        float ox = 0.f, oy = 0.f;
        if (row < N) {
            int i = rowp[row], en = rend[row];
            long long iax = 0, iay = 0;
            for (; i + 7 < en; i += 8) {
                int2 ee[8];
                f16x2 vv[8];
                #pragma unroll
                for (int u = 0; u < 8; ++u) ee[u] = colcf[i + u];
                #pragma unroll
                for (int u = 0; u < 8; ++u) vv[u] = S2[(size_t)ee[u].x * 64 + lane];
                #pragma unroll
                for (int u = 0; u < 8; ++u) {
                    float cf = __int_as_float(ee[u].y) * AGG_SCALE;
                    iax += __float2int_rn((float)vv[u].x * cf);
                    iay += __float2int_rn((float)vv[u].y * cf);
                }
            }
            for (; i < en; ++i) {
                int2 e = colcf[i];
                f16x2 v = S2[(size_t)e.x * 64 + lane];
                float cf = __int_as_float(e.y) * AGG_SCALE;
                iax += __float2int_rn((float)v.x * cf);
                iay += __float2int_rn((float)v.y * cf);
            }
            float ax = (float)iax * AGG_INV;
            float ay = (float)iay * AGG_INV;
            float dn = dis[row];
            float2 sv = X2[(size_t)row * 64 + lane];
            float d2 = dn * dn;
            ox = ax + sv.x * d2;
            oy = ay + sv.y * d2;
        }
        f16x2 h = { (_Float16)ox, (_Float16)oy };
        *(f16x2*)&Xs[r][lane * 2] = h;
    }
    __syncthreads();

    // ---- phase 2: GEMM (wave = msub x half; 4 col-tiles per wave)
    const int msub = wv >> 1, half = wv & 1;
    f32x4 acc[4];
    #pragma unroll
    for (int t = 0; t < 4; ++t) acc[t] = (f32x4){0.f, 0.f, 0.f, 0.f};

    #pragma unroll
    for (int c = 0; c < 4; ++c) {
        f16x8 a = *(const f16x8*)&Xs[msub * 16 + l15][c * 32 + kq * 8];
        #pragma unroll
        for (int t = 0; t < 4; ++t) {
            int tg = half * 4 + t;
            f16x8 b = *(const f16x8*)(B + (((size_t)c * 8 + tg) * 64 + lane) * 8);
            acc[t] = MFMA16(a, b, acc[t]);
        }
    }

    #pragma unroll
    for (int t = 0; t < 4; ++t) {
        int col = (half * 4 + t) * 16 + l15;
        float bb = bias[col];
        #pragma unroll
        for (int r = 0; r < 4; ++r) {
            int row = row0 + msub * 16 + kq * 4 + r;
            if (row < N) {
                float v = leakyf(acc[t][r] + bb);
                if (write_f32) xio[(size_t)row * 128 + col] = v;
                shout[(size_t)row * 128 + col] = (_Float16)v;
            }
        }
    }
}

// one pass: 6 K-chunks x 6 N-tiles per wave (cols half*96 + t*16 + l15)
__device__ __forceinline__ void gemm_pass6(
    const _Float16 (*X)[200], const _Float16* __restrict__ B,
    f32x4* acc, int msub, int half, int l15, int kq, int lane)
{
    #pragma unroll
    for (int t = 0; t < 6; ++t) acc[t] = (f32x4){0.f, 0.f, 0.f, 0.f};
    #pragma unroll
    for (int c = 0; c < 6; ++c) {
        f16x8 a = *(const f16x8*)&X[msub * 16 + l15][c * 32 + kq * 8];
        #pragma unroll
        for (int t = 0; t < 6; ++t) {
            f16x8 b = *(const f16x8*)(B + (((size_t)c * 12 + half * 6 + t) * 64 + lane) * 8);
            acc[t] = MFMA16(a, b, acc[t]);
        }
    }
}

// ---------------- fused tail: dnn1+dnn2+pred1(a,b)+cross+pred2+sigmoid ----
__global__ __launch_bounds__(512, 3) void tail_kernel(
    const int* __restrict__ disc, const float* __restrict__ cont,
    const float* __restrict__ Wc, const float* __restrict__ bc,
    const _Float16* __restrict__ sh,
    const _Float16* __restrict__ W1, const float* __restrict__ b1,
    const _Float16* __restrict__ W2, const float* __restrict__ b2,
    const _Float16* __restrict__ Pa, const _Float16* __restrict__ Pb,
    const float* __restrict__ pb1,
    const float* __restrict__ cw, const float* __restrict__ cvec,
    const float* __restrict__ pw2, const float* __restrict__ pb2,
    float* __restrict__ out, int N)
{
    __shared__ __attribute__((aligned(16))) _Float16 Xs[64][200];
    __shared__ __attribute__((aligned(16))) _Float16 Ts[64][200];
    __shared__ float als[64];
    __shared__ float partial[64][2];
    const int tid = threadIdx.x, lane = tid & 63, wv = tid >> 6;
    const int msub = wv >> 1, half = wv & 1, l15 = lane & 15, kq = lane >> 4;
    const int row0 = blockIdx.x * 64;

    // ---- phase A: coalesced cont tile -> Ts-as-f32 [64][100]
    float* TsF = (float*)&Ts[0][0];
    for (int idx = tid; idx < 64 * 45; idx += 512) {
        int r = idx / 45, j2 = idx - r * 45;
        int row = row0 + r;
        float2 v = make_float2(0.f, 0.f);
        if (row < N) v = ((const float2*)(cont + (size_t)row * 90))[j2];
        TsF[r * 100 + j2 * 2]     = v.x;
        TsF[r * 100 + j2 * 2 + 1] = v.y;
    }
    __syncthreads();

    // ---- phase B: embed from LDS (same f32 order) + xg shadow copy
    for (int idx = tid; idx < 64 * 44; idx += 512) {
        int r = idx / 44, j = idx - r * 44;
        int row = row0 + r;
        float v = 0.f;
        if (row < N) {
            if (j == 0) {
                const int* dr = disc + (size_t)row * 38;
                int best = dr[0], bi = 0;
                #pragma unroll
                for (int q = 1; q < 7; ++q) { int t = dr[q]; if (t > best) { best = t; bi = q; } }
                v = (float)bi;
            } else if (j < 32) {
                v = (float)disc[(size_t)row * 38 + j + 6];
            } else {
                int q = j - 32, t = q >> 2, ch = q & 3;
                float s = bc[ch];
                const float* crl = &TsF[r * 100 + t * 30];
                #pragma unroll
                for (int kk = 0; kk < 30; ++kk) s += crl[kk] * Wc[kk * 4 + ch];
                v = s;
            }
        }
        Xs[r][j] = (_Float16)v;
    }
    for (int idx = tid; idx < 64 * 32; idx += 512) {   // sh: 128 f16 = 32 x 8B
        int r = idx >> 5, q = idx & 31;
        int row = row0 + r;
        uint2 v = {0u, 0u};
        if (row < N) v = *(const uint2*)(sh + (size_t)row * 128 + q * 4);
        *(uint2*)&Xs[r][44 + q * 4] = v;
    }
    for (int idx = tid; idx < 64 * 28; idx += 512) {
        int r = idx / 28, j = idx - r * 28;
        Xs[r][172 + j] = (_Float16)0.f;
    }
    __syncthreads();

    // per-row cross scalars: xl2 = als*x0 + (b1c+b2c)
    {
        int row = tid >> 3, sub = tid & 7;
        float d1 = 0.f, d2 = 0.f;
        for (int col = sub; col < 172; col += 8) {
            float x = (float)Xs[row][col];
            d1 += x * cw[col];
            d2 += x * cw[172 + col];
        }
        #pragma unroll
        for (int off = 1; off < 8; off <<= 1) {
            d1 += __shfl_xor(d1, off, 64);
            d2 += __shfl_xor(d2, off, 64);
        }
        if (sub == 0) {
            float a1 = 1.f + d1;
            als[row] = a1 + a1 * d2 + cvec[176];
        }
    }

    f32x4 accA[6], accB[6];

    // dnn1: Xs -> Ts
    gemm_pass6(Xs, W1, accA, msub, half, l15, kq, lane);
    #pragma unroll
    for (int t = 0; t < 6; ++t) {
        int col = half * 96 + t * 16 + l15;
        #pragma unroll
        for (int r = 0; r < 4; ++r) {
            int row = msub * 16 + kq * 4 + r;
            float v = (col < 172) ? leakyf(accA[t][r] + b1[col]) : 0.f;
            Ts[row][col] = (_Float16)v;
        }
    }
    __syncthreads();
    // dnn2: Ts -> Ts (in place)
    gemm_pass6(Ts, W2, accA, msub, half, l15, kq, lane);
    __syncthreads();
    #pragma unroll
    for (int t = 0; t < 6; ++t) {
        int col = half * 96 + t * 16 + l15;
        #pragma unroll
        for (int r = 0; r < 4; ++r) {
            int row = msub * 16 + kq * 4 + r;
            float v = (col < 172) ? leakyf(accA[t][r] + b2[col]) : 0.f;
            Ts[row][col] = (_Float16)v;
        }
    }
    __syncthreads();

    // pred1: accA = xdeep@Pa (from Ts), accB = x0@Pb (from Xs)
    gemm_pass6(Ts, Pa, accA, msub, half, l15, kq, lane);
    gemm_pass6(Xs, Pb, accB, msub, half, l15, kq, lane);

    // epilogue: pre = accA + pb1 + als*accB + cvec -> leaky -> . pw2 -> sigmoid
    float part[4] = {0.f, 0.f, 0.f, 0.f};
    #pragma unroll
    for (int t = 0; t < 6; ++t) {
        int col = half * 96 + t * 16 + l15;
        if (col < 172) {
            float cv = cvec[col] + pb1[col], w2v = pw2[col];
            #pragma unroll
            for (int r = 0; r < 4; ++r) {
                int row = msub * 16 + kq * 4 + r;
                float pre = accA[t][r] + als[row] * accB[t][r] + cv;
                part[r] += leakyf(pre) * w2v;
            }
        }
    }
    #pragma unroll
    for (int r = 0; r < 4; ++r) {
        #pragma unroll
        for (int off = 1; off < 16; off <<= 1)
            part[r] += __shfl_xor(part[r], off, 64);
    }
    if (l15 == 0) {
        #pragma unroll
        for (int r = 0; r < 4; ++r)
            partial[msub * 16 + kq * 4 + r][half] = part[r];
    }
    __syncthreads();
    if (tid < 64) {
        int grow = row0 + tid;
        if (grow < N) {
            float s = partial[tid][0] + partial[tid][1] + pb2[0];
            out[grow] = 1.f / (1.f + expf(-s));
        }
    }
}

extern "C" void kernel_launch(void* const* d_in, const int* in_sizes, int n_in,
                              void* d_out, int out_size, void* d_ws, size_t ws_size,
                              hipStream_t stream)
{
    const int*   disc    = (const int*)d_in[0];
    const float* cont    = (const float*)d_in[1];
    const int*   eidx    = (const int*)d_in[2];
    const float* emb_W   = (const float*)d_in[5];
    const float* emb_b   = (const float*)d_in[6];
    const float* g0_W    = (const float*)d_in[7];
    const float* g0_b    = (const float*)d_in[8];
    const float* gcn1_W  = (const float*)d_in[9];
    const float* gcn1_b  = (const float*)d_in[10];
    const float* gcn2_W  = (const float*)d_in[11];
    const float* gcn2_b  = (const float*)d_in[12];
    const float* dnn_W1  = (const float*)d_in[13];
    const float* dnn_b1  = (const float*)d_in[14];
    const float* dnn_W2  = (const float*)d_in[15];
    const float* dnn_b2  = (const float*)d_in[16];
    const float* cross_w = (const float*)d_in[17];
    const float* cross_b = (const float*)d_in[18];
    const float* pred_W1 = (const float*)d_in[19];
    const float* pred_b1 = (const float*)d_in[20];
    const float* pred_W2 = (const float*)d_in[21];
    const float* pred_b2 = (const float*)d_in[22];

    const int N = in_sizes[0] / 38;
    const int E = in_sizes[2] / 2;
    const int* src = eidx;
    const int* dst = eidx + E;

    // ---- workspace (~117.7 MB — proven R15 layout) ----
    float* xgF     = (float*)d_ws;                        // [N,128] f32 (in-place)
    _Float16* shA  = (_Float16*)(xgF + (size_t)128 * N);  // [N,128] f16
    _Float16* shB  = shA + (size_t)128 * N;               // [N,128] f16
    float* dis  = (float*)(shB + (size_t)128 * N);        // [N]
    int* cnt    = (int*)(dis + N);                        // [N]
    int* rowp   = cnt + N;                                // [N]
    int* curs   = rowp + N;                               // [N]
    int* bsum   = curs + N;                               // [512]
    int2* colcf = (int2*)(((size_t)(bsum + 512) + 15) & ~(size_t)15);  // [E]
    _Float16* wf = (_Float16*)(colcf + E);
    _Float16* G1f = wf;              // 4*8*512   = 16384
    _Float16* G2f = G1f + 16384;
    _Float16* W1f = G2f + 16384;     // 6*12*512  = 36864
    _Float16* W2f = W1f + 36864;
    _Float16* Paf = W2f + 36864;
    _Float16* Pbf = Paf + 36864;
    float* cvec   = (float*)(Pbf + 36864);                // [192]

    auto cdiv = [](int a, int b) { return (a + b - 1) / b; };
    const int nb = cdiv(N, 256);

    // weight prep: all planes + cvec in ONE launch
    wprep_kernel<<<705, 256, 0, stream>>>(
        gcn1_W, gcn2_W, dnn_W1, dnn_W2, pred_W1, cross_b, cross_w,
        G1f, G2f, W1f, W2f, Paf, Pbf, cvec);

    // CSR build (+ per-edge coeff)
    hipMemsetAsync(cnt, 0, (size_t)N * sizeof(int), stream);
    cnt_edge_kernel<<<cdiv(E, 256), 256, 0, stream>>>(dst, cnt, E);
    scan1_kernel<<<nb, 256, 0, stream>>>(cnt, curs, bsum, N);
    scan2_kernel<<<1, 64, 0, stream>>>(bsum, nb);
    scan3_kernel<<<nb, 256, 0, stream>>>(curs, cnt, bsum, rowp, curs, dis, N);
    fill_kernel<<<cdiv(E, 256), 256, 0, stream>>>(src, dst, dis, curs, colcf, E);

    // g0 -> xgF (f32) + shA (f16)
    g0_kernel<<<cdiv(N, 32), 256, 0, stream>>>(disc, cont, emb_W, emb_b, g0_W, g0_b,
                                               xgF, shA, N);

    // GCN L1: gather shA, self xgF, write xgF (in-place) + shB
    gcn_fused<<<cdiv(N, 64), 512, 0, stream>>>(shA, xgF, colcf, rowp, curs, dis,
                                               G1f, gcn1_b, shB, 1, N);
    // GCN L2: gather shB, self xgF, write shA only (f32 result dead)
    gcn_fused<<<cdiv(N, 64), 512, 0, stream>>>(shB, xgF, colcf, rowp, curs, dis,
                                               G2f, gcn2_b, shA, 0, N);

    // fused tail -> out (stages xg from shA — bit-identical to f32->f16 staging)
    tail_kernel<<<cdiv(N, 64), 512, 0, stream>>>(
        disc, cont, emb_W, emb_b, shA,
        W1f, dnn_b1, W2f, dnn_b2, Paf, Pbf, pred_b1,
        cross_w, cvec, pred_W2, pred_b2, (float*)d_out, N);
}

// Round 18
// 549.662 us; speedup vs baseline: 1.1257x; 1.0372x over previous
//
#include <hip/hip_runtime.h>
#include <math.h>

// ---------------------------------------------------------------------------
// DCN_89859305767621  Round 18 = R17 + f16-only graph path:
//  - xgF (f32 plane) deleted; self-loop terms read the f16 shadow (only new
//    rounding: self-loop component, ~5e-4 rel; margin 4.5x). Saves ~150 MB
//    of traffic across g0/gcn1/gcn2. Footprint ~66 MB.
//  - everything else byte-identical to R17 (570us, 3.9e-3, deterministic).
// ---------------------------------------------------------------------------

typedef __attribute__((ext_vector_type(8))) _Float16 f16x8;
typedef __attribute__((ext_vector_type(4))) _Float16 f16x4;
typedef __attribute__((ext_vector_type(2))) _Float16 f16x2;
typedef __attribute__((ext_vector_type(4))) float f32x4;

__device__ __forceinline__ float leakyf(float v) { return v > 0.f ? v : 0.01f * v; }

#define MFMA16(a, b, c) __builtin_amdgcn_mfma_f32_16x16x32_f16((a), (b), (c), 0, 0, 0)
#define AGG_SCALE 1048576.0f   // 2^20
#define AGG_INV   9.5367431640625e-07f

// ---------------- CSR build ----------------
__global__ __launch_bounds__(256) void cnt_edge_kernel(const int* __restrict__ dst,
                                                       int* __restrict__ cnt, int E)
{
    int i = blockIdx.x * 256 + threadIdx.x;
    if (i < E) atomicAdd(&cnt[dst[i]], 1);
}

__global__ __launch_bounds__(256) void scan1_kernel(const int* __restrict__ cnt,
                                                    int* __restrict__ incl,
                                                    int* __restrict__ bsum, int N)
{
    __shared__ int s[256];
    int tid = threadIdx.x;
    int i = blockIdx.x * 256 + tid;
    s[tid] = (i < N) ? cnt[i] : 0;
    __syncthreads();
    #pragma unroll
    for (int off = 1; off < 256; off <<= 1) {
        int t = (tid >= off) ? s[tid - off] : 0;
        __syncthreads();
        s[tid] += t;
        __syncthreads();
    }
    if (i < N) incl[i] = s[tid];
    if (tid == 255) bsum[blockIdx.x] = s[255];
}

__global__ void scan2_kernel(int* __restrict__ bsum, int nb)   // 1 block, 64 threads
{
    int lane = threadIdx.x & 63;
    int run = 0;
    for (int base = 0; base < nb; base += 64) {
        int i = base + lane;
        int orig = (i < nb) ? bsum[i] : 0;
        int v = orig;
        #pragma unroll
        for (int off = 1; off < 64; off <<= 1) {
            int t = __shfl_up(v, off, 64);
            if (lane >= off) v += t;
        }
        if (i < nb) bsum[i] = run + v - orig;
        run += __shfl(v, 63, 64);
    }
}

// row_ptr/cursor + dis = rsqrt(deg+1)
__global__ __launch_bounds__(256) void scan3_kernel(const int* __restrict__ incl,
                                                    const int* __restrict__ cnt,
                                                    const int* __restrict__ bsum,
                                                    int* __restrict__ row_ptr,
                                                    int* __restrict__ cursor,
                                                    float* __restrict__ dis, int N)
{
    int i = blockIdx.x * 256 + threadIdx.x;
    if (i < N) {
        int v = incl[i] - cnt[i] + bsum[i >> 8];
        row_ptr[i] = v;
        cursor[i] = v;
        dis[i] = rsqrtf((float)cnt[i] + 1.0f);
    }
}

// fill CSR adjacency with fused edge coefficient: colcf[p] = {src, dis_s*dis_d}
__global__ __launch_bounds__(256) void fill_kernel(const int* __restrict__ src,
                                                   const int* __restrict__ dst,
                                                   const float* __restrict__ dis,
                                                   int* __restrict__ cursor,
                                                   int2* __restrict__ colcf, int E)
{
    int e = blockIdx.x * 256 + threadIdx.x;
    if (e < E) {
        int s = src[e], d = dst[e];
        int p = atomicAdd(&cursor[d], 1);
        colcf[p] = make_int2(s, __float_as_int(dis[s] * dis[d]));
    }
}

// ---------------- weight prep: all 6 fp16 fragment planes + cvec, 1 launch --
__global__ __launch_bounds__(256) void wprep_kernel(
    const float* __restrict__ gcn1_W, const float* __restrict__ gcn2_W,
    const float* __restrict__ dnn_W1, const float* __restrict__ dnn_W2,
    const float* __restrict__ pred_W1,
    const float* __restrict__ cb, const float* __restrict__ cw,
    _Float16* __restrict__ G1f, _Float16* __restrict__ G2f,
    _Float16* __restrict__ W1f, _Float16* __restrict__ W2f,
    _Float16* __restrict__ Paf, _Float16* __restrict__ Pbf,
    float* __restrict__ cvec)
{
    int b = blockIdx.x;
    if (b == 704) {
        int col = threadIdx.x;
        if (col < 176) {
            float s = 0.f;
            if (col < 172)
                for (int k = 0; k < 172; ++k)
                    s += (cb[k] + cb[172 + k]) * pred_W1[(size_t)(172 + k) * 172 + col];
            cvec[col] = s;
        } else if (col == 176) {
            float c = 0.f;
            for (int k = 0; k < 172; ++k) c += cb[k] * cw[172 + k];
            cvec[176] = c;
        }
        return;
    }
    const float* W; _Float16* Wf; int K, Ncol, NT, base;
    if (b < 64)       { W = gcn1_W; Wf = G1f; K = 128; Ncol = 128; NT = 8;  base = 0;   }
    else if (b < 128) { W = gcn2_W; Wf = G2f; K = 128; Ncol = 128; NT = 8;  base = 64;  }
    else if (b < 272) { W = dnn_W1; Wf = W1f; K = 172; Ncol = 172; NT = 12; base = 128; }
    else if (b < 416) { W = dnn_W2; Wf = W2f; K = 172; Ncol = 172; NT = 12; base = 272; }
    else if (b < 560) { W = pred_W1; Wf = Paf; K = 172; Ncol = 172; NT = 12; base = 416; }
    else              { W = pred_W1 + (size_t)172 * 172; Wf = Pbf; K = 172; Ncol = 172; NT = 12; base = 560; }
    int idx = (b - base) * 256 + threadIdx.x;
    int e = idx & 7;
    int lane = (idx >> 3) & 63;
    int ct = idx >> 9;
    int t = ct % NT, c = ct / NT;
    int col = t * 16 + (lane & 15);
    int k = c * 32 + (lane >> 4) * 8 + e;
    float x = (k < K && col < Ncol) ? W[(size_t)k * Ncol + col] : 0.f;
    Wf[idx] = (_Float16)x;
}

// ---------------- g0: embed -> [N,44]@[44,128]+b, leaky -> sh f16 ---------
__global__ __launch_bounds__(256) void g0_kernel(
    const int* __restrict__ disc, const float* __restrict__ cont,
    const float* __restrict__ Wc, const float* __restrict__ bc,
    const float* __restrict__ W, const float* __restrict__ bias,
    _Float16* __restrict__ sh, int N)
{
    constexpr int TM = 32, K = 44, RB = 8;
    __shared__ float Alds[TM][K];
    __shared__ float Wlds[K][128];
    const int tid = threadIdx.x, lane = tid & 63, wv = tid >> 6;
    const int row0 = blockIdx.x * TM;

    for (int idx = tid; idx < TM * 38; idx += 256) {
        int r = idx / 38, j = idx - r * 38;
        int row = row0 + r;
        if (j == 0) {
            float o = 0.f;
            if (row < N) {
                const int* dr = disc + (size_t)row * 38;
                int best = dr[0], bi = 0;
                #pragma unroll
                for (int q = 1; q < 7; ++q) { int v = dr[q]; if (v > best) { best = v; bi = q; } }
                o = (float)bi;
            }
            Alds[r][0] = o;
        } else if (j >= 7) {
            Alds[r][j - 6] = (row < N) ? (float)disc[(size_t)row * 38 + j] : 0.f;
        }
    }
    for (int idx = tid; idx < TM * 12; idx += 256) {
        int r = idx / 12, q = idx - r * 12;
        int t = q >> 2, ch = q & 3;
        int row = row0 + r;
        float s = 0.f;
        if (row < N) {
            s = bc[ch];
            const float* cr = cont + (size_t)row * 90 + t * 30;
            #pragma unroll
            for (int j = 0; j < 30; ++j) s += cr[j] * Wc[j * 4 + ch];
        }
        Alds[r][32 + t * 4 + ch] = s;
    }
    for (int idx = tid; idx < K * 32; idx += 256) {
        int k = idx >> 5, c4 = idx & 31;
        ((float4*)&Wlds[k][0])[c4] = ((const float4*)W)[idx];
    }
    __syncthreads();

    float acc[RB][2];
    float b0 = bias[lane], b1 = bias[lane + 64];
    #pragma unroll
    for (int r = 0; r < RB; ++r) { acc[r][0] = b0; acc[r][1] = b1; }

    for (int k = 0; k < K; ++k) {
        float w0 = Wlds[k][lane], w1 = Wlds[k][lane + 64];
        #pragma unroll
        for (int r = 0; r < RB; ++r) {
            float a = Alds[wv * RB + r][k];
            acc[r][0] += a * w0;
            acc[r][1] += a * w1;
        }
    }
    #pragma unroll
    for (int r = 0; r < RB; ++r) {
        int row = row0 + wv * RB + r;
        if (row < N) {
            sh[(size_t)row * 128 + lane]      = (_Float16)leakyf(acc[r][0]);
            sh[(size_t)row * 128 + lane + 64] = (_Float16)leakyf(acc[r][1]);
        }
    }
}

// ---------------- fused GCN layer: shout = leaky(AGG(shin) @ G + b) --------
// gather + self-loop both read the f16 shadow; int64 deterministic sum.
__global__ __launch_bounds__(512, 4) void gcn_fused(
    const _Float16* __restrict__ shin, const int2* __restrict__ colcf,
    const int* __restrict__ rowp, const int* __restrict__ rend,
    const float* __restrict__ dis, const _Float16* __restrict__ B,
    const float* __restrict__ bias, _Float16* __restrict__ shout, int N)
{
    __shared__ __attribute__((aligned(16))) _Float16 Xs[64][136];
    const int tid = threadIdx.x, lane = tid & 63, wv = tid >> 6;
    const int l15 = lane & 15, kq = lane >> 4;
    const int row0 = blockIdx.x * 64;
    const f16x2* S2 = (const f16x2*)shin;

    // ---- phase 1: gather + self-loop (f16 rows), int64 sum
    #pragma unroll 1
    for (int rr = 0; rr < 8; ++rr) {
        const int r = (wv << 3) + rr;
        const int row = row0 + r;
        float ox = 0.f, oy = 0.f;
        if (row < N) {
            int i = rowp[row], en = rend[row];
            long long iax = 0, iay = 0;
            for (; i + 7 < en; i += 8) {
                int2 ee[8];
                f16x2 vv[8];
                #pragma unroll
                for (int u = 0; u < 8; ++u) ee[u] = colcf[i + u];
                #pragma unroll
                for (int u = 0; u < 8; ++u) vv[u] = S2[(size_t)ee[u].x * 64 + lane];
                #pragma unroll
                for (int u = 0; u < 8; ++u) {
                    float cf = __int_as_float(ee[u].y) * AGG_SCALE;
                    iax += __float2int_rn((float)vv[u].x * cf);
                    iay += __float2int_rn((float)vv[u].y * cf);
                }
            }
            for (; i < en; ++i) {
                int2 e = colcf[i];
                f16x2 v = S2[(size_t)e.x * 64 + lane];
                float cf = __int_as_float(e.y) * AGG_SCALE;
                iax += __float2int_rn((float)v.x * cf);
                iay += __float2int_rn((float)v.y * cf);
            }
            float ax = (float)iax * AGG_INV;
            float ay = (float)iay * AGG_INV;
            float dn = dis[row];
            f16x2 sv = S2[(size_t)row * 64 + lane];
            float d2 = dn * dn;
            ox = ax + (float)sv.x * d2;
            oy = ay + (float)sv.y * d2;
        }
        f16x2 h = { (_Float16)ox, (_Float16)oy };
        *(f16x2*)&Xs[r][lane * 2] = h;
    }
    __syncthreads();

    // ---- phase 2: GEMM (wave = msub x half; 4 col-tiles per wave)
    const int msub = wv >> 1, half = wv & 1;
    f32x4 acc[4];
    #pragma unroll
    for (int t = 0; t < 4; ++t) acc[t] = (f32x4){0.f, 0.f, 0.f, 0.f};

    #pragma unroll
    for (int c = 0; c < 4; ++c) {
        f16x8 a = *(const f16x8*)&Xs[msub * 16 + l15][c * 32 + kq * 8];
        #pragma unroll
        for (int t = 0; t < 4; ++t) {
            int tg = half * 4 + t;
            f16x8 b = *(const f16x8*)(B + (((size_t)c * 8 + tg) * 64 + lane) * 8);
            acc[t] = MFMA16(a, b, acc[t]);
        }
    }

    #pragma unroll
    for (int t = 0; t < 4; ++t) {
        int col = (half * 4 + t) * 16 + l15;
        float bb = bias[col];
        #pragma unroll
        for (int r = 0; r < 4; ++r) {
            int row = row0 + msub * 16 + kq * 4 + r;
            if (row < N)
                shout[(size_t)row * 128 + col] = (_Float16)leakyf(acc[t][r] + bb);
        }
    }
}

// one pass: 6 K-chunks x 6 N-tiles per wave (cols half*96 + t*16 + l15)
__device__ __forceinline__ void gemm_pass6(
    const _Float16 (*X)[200], const _Float16* __restrict__ B,
    f32x4* acc, int msub, int half, int l15, int kq, int lane)
{
    #pragma unroll
    for (int t = 0; t < 6; ++t) acc[t] = (f32x4){0.f, 0.f, 0.f, 0.f};
    #pragma unroll
    for (int c = 0; c < 6; ++c) {
        f16x8 a = *(const f16x8*)&X[msub * 16 + l15][c * 32 + kq * 8];
        #pragma unroll
        for (int t = 0; t < 6; ++t) {
            f16x8 b = *(const f16x8*)(B + (((size_t)c * 12 + half * 6 + t) * 64 + lane) * 8);
            acc[t] = MFMA16(a, b, acc[t]);
        }
    }
}

// ---------------- fused tail: dnn1+dnn2+pred1(a,b)+cross+pred2+sigmoid ----
__global__ __launch_bounds__(512, 3) void tail_kernel(
    const int* __restrict__ disc, const float* __restrict__ cont,
    const float* __restrict__ Wc, const float* __restrict__ bc,
    const _Float16* __restrict__ sh,
    const _Float16* __restrict__ W1, const float* __restrict__ b1,
    const _Float16* __restrict__ W2, const float* __restrict__ b2,
    const _Float16* __restrict__ Pa, const _Float16* __restrict__ Pb,
    const float* __restrict__ pb1,
    const float* __restrict__ cw, const float* __restrict__ cvec,
    const float* __restrict__ pw2, const float* __restrict__ pb2,
    float* __restrict__ out, int N)
{
    __shared__ __attribute__((aligned(16))) _Float16 Xs[64][200];
    __shared__ __attribute__((aligned(16))) _Float16 Ts[64][200];
    __shared__ float als[64];
    __shared__ float partial[64][2];
    const int tid = threadIdx.x, lane = tid & 63, wv = tid >> 6;
    const int msub = wv >> 1, half = wv & 1, l15 = lane & 15, kq = lane >> 4;
    const int row0 = blockIdx.x * 64;

    // ---- phase A: coalesced cont tile -> Ts-as-f32 [64][100]
    float* TsF = (float*)&Ts[0][0];
    for (int idx = tid; idx < 64 * 45; idx += 512) {
        int r = idx / 45, j2 = idx - r * 45;
        int row = row0 + r;
        float2 v = make_float2(0.f, 0.f);
        if (row < N) v = ((const float2*)(cont + (size_t)row * 90))[j2];
        TsF[r * 100 + j2 * 2]     = v.x;
        TsF[r * 100 + j2 * 2 + 1] = v.y;
    }
    __syncthreads();

    // ---- phase B: embed from LDS (same f32 order) + xg shadow copy
    for (int idx = tid; idx < 64 * 44; idx += 512) {
        int r = idx / 44, j = idx - r * 44;
        int row = row0 + r;
        float v = 0.f;
        if (row < N) {
            if (j == 0) {
                const int* dr = disc + (size_t)row * 38;
                int best = dr[0], bi = 0;
                #pragma unroll
                for (int q = 1; q < 7; ++q) { int t = dr[q]; if (t > best) { best = t; bi = q; } }
                v = (float)bi;
            } else if (j < 32) {
                v = (float)disc[(size_t)row * 38 + j + 6];
            } else {
                int q = j - 32, t = q >> 2, ch = q & 3;
                float s = bc[ch];
                const float* crl = &TsF[r * 100 + t * 30];
                #pragma unroll
                for (int kk = 0; kk < 30; ++kk) s += crl[kk] * Wc[kk * 4 + ch];
                v = s;
            }
        }
        Xs[r][j] = (_Float16)v;
    }
    for (int idx = tid; idx < 64 * 32; idx += 512) {   // sh: 128 f16 = 32 x 8B
        int r = idx >> 5, q = idx & 31;
        int row = row0 + r;
        uint2 v = {0u, 0u};
        if (row < N) v = *(const uint2*)(sh + (size_t)row * 128 + q * 4);
        *(uint2*)&Xs[r][44 + q * 4] = v;
    }
    for (int idx = tid; idx < 64 * 28; idx += 512) {
        int r = idx / 28, j = idx - r * 28;
        Xs[r][172 + j] = (_Float16)0.f;
    }
    __syncthreads();

    // per-row cross scalars: xl2 = als*x0 + (b1c+b2c)
    {
        int row = tid >> 3, sub = tid & 7;
        float d1 = 0.f, d2 = 0.f;
        for (int col = sub; col < 172; col += 8) {
            float x = (float)Xs[row][col];
            d1 += x * cw[col];
            d2 += x * cw[172 + col];
        }
        #pragma unroll
        for (int off = 1; off < 8; off <<= 1) {
            d1 += __shfl_xor(d1, off, 64);
            d2 += __shfl_xor(d2, off, 64);
        }
        if (sub == 0) {
            float a1 = 1.f + d1;
            als[row] = a1 + a1 * d2 + cvec[176];
        }
    }

    f32x4 accA[6], accB[6];

    // dnn1: Xs -> Ts
    gemm_pass6(Xs, W1, accA, msub, half, l15, kq, lane);
    #pragma unroll
    for (int t = 0; t < 6; ++t) {
        int col = half * 96 + t * 16 + l15;
        #pragma unroll
        for (int r = 0; r < 4; ++r) {
            int row = msub * 16 + kq * 4 + r;
            float v = (col < 172) ? leakyf(accA[t][r] + b1[col]) : 0.f;
            Ts[row][col] = (_Float16)v;
        }
    }
    __syncthreads();
    // dnn2: Ts -> Ts (in place)
    gemm_pass6(Ts, W2, accA, msub, half, l15, kq, lane);
    __syncthreads();
    #pragma unroll
    for (int t = 0; t < 6; ++t) {
        int col = half * 96 + t * 16 + l15;
        #pragma unroll
        for (int r = 0; r < 4; ++r) {
            int row = msub * 16 + kq * 4 + r;
            float v = (col < 172) ? leakyf(accA[t][r] + b2[col]) : 0.f;
            Ts[row][col] = (_Float16)v;
        }
    }
    __syncthreads();

    // pred1: accA = xdeep@Pa (from Ts), accB = x0@Pb (from Xs)
    gemm_pass6(Ts, Pa, accA, msub, half, l15, kq, lane);
    gemm_pass6(Xs, Pb, accB, msub, half, l15, kq, lane);

    // epilogue: pre = accA + pb1 + als*accB + cvec -> leaky -> . pw2 -> sigmoid
    float part[4] = {0.f, 0.f, 0.f, 0.f};
    #pragma unroll
    for (int t = 0; t < 6; ++t) {
        int col = half * 96 + t * 16 + l15;
        if (col < 172) {
            float cv = cvec[col] + pb1[col], w2v = pw2[col];
            #pragma unroll
            for (int r = 0; r < 4; ++r) {
                int row = msub * 16 + kq * 4 + r;
                float pre = accA[t][r] + als[row] * accB[t][r] + cv;
                part[r] += leakyf(pre) * w2v;
            }
        }
    }
    #pragma unroll
    for (int r = 0; r < 4; ++r) {
        #pragma unroll
        for (int off = 1; off < 16; off <<= 1)
            part[r] += __shfl_xor(part[r], off, 64);
    }
    if (l15 == 0) {
        #pragma unroll
        for (int r = 0; r < 4; ++r)
            partial[msub * 16 + kq * 4 + r][half] = part[r];
    }
    __syncthreads();
    if (tid < 64) {
        int grow = row0 + tid;
        if (grow < N) {
            float s = partial[tid][0] + partial[tid][1] + pb2[0];
            out[grow] = 1.f / (1.f + expf(-s));
        }
    }
}

extern "C" void kernel_launch(void* const* d_in, const int* in_sizes, int n_in,
                              void* d_out, int out_size, void* d_ws, size_t ws_size,
                              hipStream_t stream)
{
    const int*   disc    = (const int*)d_in[0];
    const float* cont    = (const float*)d_in[1];
    const int*   eidx    = (const int*)d_in[2];
    const float* emb_W   = (const float*)d_in[5];
    const float* emb_b   = (const float*)d_in[6];
    const float* g0_W    = (const float*)d_in[7];
    const float* g0_b    = (const float*)d_in[8];
    const float* gcn1_W  = (const float*)d_in[9];
    const float* gcn1_b  = (const float*)d_in[10];
    const float* gcn2_W  = (const float*)d_in[11];
    const float* gcn2_b  = (const float*)d_in[12];
    const float* dnn_W1  = (const float*)d_in[13];
    const float* dnn_b1  = (const float*)d_in[14];
    const float* dnn_W2  = (const float*)d_in[15];
    const float* dnn_b2  = (const float*)d_in[16];
    const float* cross_w = (const float*)d_in[17];
    const float* cross_b = (const float*)d_in[18];
    const float* pred_W1 = (const float*)d_in[19];
    const float* pred_b1 = (const float*)d_in[20];
    const float* pred_W2 = (const float*)d_in[21];
    const float* pred_b2 = (const float*)d_in[22];

    const int N = in_sizes[0] / 38;
    const int E = in_sizes[2] / 2;
    const int* src = eidx;
    const int* dst = eidx + E;

    // ---- workspace (~66 MB) ----
    _Float16* shA = (_Float16*)d_ws;                      // [N,128] f16
    _Float16* shB = shA + (size_t)128 * N;                // [N,128] f16
    float* dis  = (float*)(shB + (size_t)128 * N);        // [N]
    int* cnt    = (int*)(dis + N);                        // [N]
    int* rowp   = cnt + N;                                // [N]
    int* curs   = rowp + N;                               // [N]
    int* bsum   = curs + N;                               // [512]
    int2* colcf = (int2*)(((size_t)(bsum + 512) + 15) & ~(size_t)15);  // [E]
    _Float16* wf = (_Float16*)(colcf + E);
    _Float16* G1f = wf;              // 4*8*512   = 16384
    _Float16* G2f = G1f + 16384;
    _Float16* W1f = G2f + 16384;     // 6*12*512  = 36864
    _Float16* W2f = W1f + 36864;
    _Float16* Paf = W2f + 36864;
    _Float16* Pbf = Paf + 36864;
    float* cvec   = (float*)(Pbf + 36864);                // [192]

    auto cdiv = [](int a, int b) { return (a + b - 1) / b; };
    const int nb = cdiv(N, 256);

    // weight prep: all planes + cvec in ONE launch
    wprep_kernel<<<705, 256, 0, stream>>>(
        gcn1_W, gcn2_W, dnn_W1, dnn_W2, pred_W1, cross_b, cross_w,
        G1f, G2f, W1f, W2f, Paf, Pbf, cvec);

    // CSR build (+ per-edge coeff)
    hipMemsetAsync(cnt, 0, (size_t)N * sizeof(int), stream);
    cnt_edge_kernel<<<cdiv(E, 256), 256, 0, stream>>>(dst, cnt, E);
    scan1_kernel<<<nb, 256, 0, stream>>>(cnt, curs, bsum, N);
    scan2_kernel<<<1, 64, 0, stream>>>(bsum, nb);
    scan3_kernel<<<nb, 256, 0, stream>>>(curs, cnt, bsum, rowp, curs, dis, N);
    fill_kernel<<<cdiv(E, 256), 256, 0, stream>>>(src, dst, dis, curs, colcf, E);

    // g0 -> shA (f16)
    g0_kernel<<<cdiv(N, 32), 256, 0, stream>>>(disc, cont, emb_W, emb_b, g0_W, g0_b,
                                               shA, N);

    // GCN L1: shA -> shB ; GCN L2: shB -> shA
    gcn_fused<<<cdiv(N, 64), 512, 0, stream>>>(shA, colcf, rowp, curs, dis,
                                               G1f, gcn1_b, shB, N);
    gcn_fused<<<cdiv(N, 64), 512, 0, stream>>>(shB, colcf, rowp, curs, dis,
                                               G2f, gcn2_b, shA, N);

    // fused tail -> out
    tail_kernel<<<cdiv(N, 64), 512, 0, stream>>>(
        disc, cont, emb_W, emb_b, shA,
        W1f, dnn_b1, W2f, dnn_b2, Paf, Pbf, pred_b1,
        cross_w, cvec, pred_W2, pred_b2, (float*)d_out, N);
}

// Round 21
// 530.964 us; speedup vs baseline: 1.1653x; 1.0352x over previous
//
#include <hip/hip_runtime.h>
#include <math.h>

// ---------------------------------------------------------------------------
// DCN_89859305767621  Round 21 = Round 19 resubmit (2x infra failure):
//  - tail GEMM waves remapped (4 msub x 2 half) -> (2 row-pairs x 4 tile-grps):
//    each wave loads a B-fragment once and feeds 2 MFMAs (2 row-subtiles).
//    L2 B-fragment traffic halves; per-accumulator MFMA order identical
//    -> bit-identical output.
//  - everything else frozen from R18 (549us, 3.9e-3, deterministic).
// ---------------------------------------------------------------------------

typedef __attribute__((ext_vector_type(8))) _Float16 f16x8;
typedef __attribute__((ext_vector_type(4))) _Float16 f16x4;
typedef __attribute__((ext_vector_type(2))) _Float16 f16x2;
typedef __attribute__((ext_vector_type(4))) float f32x4;

__device__ __forceinline__ float leakyf(float v) { return v > 0.f ? v : 0.01f * v; }

#define MFMA16(a, b, c) __builtin_amdgcn_mfma_f32_16x16x32_f16((a), (b), (c), 0, 0, 0)
#define AGG_SCALE 1048576.0f   // 2^20
#define AGG_INV   9.5367431640625e-07f

// ---------------- CSR build ----------------
__global__ __launch_bounds__(256) void cnt_edge_kernel(const int* __restrict__ dst,
                                                       int* __restrict__ cnt, int E)
{
    int i = blockIdx.x * 256 + threadIdx.x;
    if (i < E) atomicAdd(&cnt[dst[i]], 1);
}

__global__ __launch_bounds__(256) void scan1_kernel(const int* __restrict__ cnt,
                                                    int* __restrict__ incl,
                                                    int* __restrict__ bsum, int N)
{
    __shared__ int s[256];
    int tid = threadIdx.x;
    int i = blockIdx.x * 256 + tid;
    s[tid] = (i < N) ? cnt[i] : 0;
    __syncthreads();
    #pragma unroll
    for (int off = 1; off < 256; off <<= 1) {
        int t = (tid >= off) ? s[tid - off] : 0;
        __syncthreads();
        s[tid] += t;
        __syncthreads();
    }
    if (i < N) incl[i] = s[tid];
    if (tid == 255) bsum[blockIdx.x] = s[255];
}

__global__ void scan2_kernel(int* __restrict__ bsum, int nb)   // 1 block, 64 threads
{
    int lane = threadIdx.x & 63;
    int run = 0;
    for (int base = 0; base < nb; base += 64) {
        int i = base + lane;
        int orig = (i < nb) ? bsum[i] : 0;
        int v = orig;
        #pragma unroll
        for (int off = 1; off < 64; off <<= 1) {
            int t = __shfl_up(v, off, 64);
            if (lane >= off) v += t;
        }
        if (i < nb) bsum[i] = run + v - orig;
        run += __shfl(v, 63, 64);
    }
}

// row_ptr/cursor + dis = rsqrt(deg+1)
__global__ __launch_bounds__(256) void scan3_kernel(const int* __restrict__ incl,
                                                    const int* __restrict__ cnt,
                                                    const int* __restrict__ bsum,
                                                    int* __restrict__ row_ptr,
                                                    int* __restrict__ cursor,
                                                    float* __restrict__ dis, int N)
{
    int i = blockIdx.x * 256 + threadIdx.x;
    if (i < N) {
        int v = incl[i] - cnt[i] + bsum[i >> 8];
        row_ptr[i] = v;
        cursor[i] = v;
        dis[i] = rsqrtf((float)cnt[i] + 1.0f);
    }
}

// fill CSR adjacency with fused edge coefficient: colcf[p] = {src, dis_s*dis_d}
__global__ __launch_bounds__(256) void fill_kernel(const int* __restrict__ src,
                                                   const int* __restrict__ dst,
                                                   const float* __restrict__ dis,
                                                   int* __restrict__ cursor,
                                                   int2* __restrict__ colcf, int E)
{
    int e = blockIdx.x * 256 + threadIdx.x;
    if (e < E) {
        int s = src[e], d = dst[e];
        int p = atomicAdd(&cursor[d], 1);
        colcf[p] = make_int2(s, __float_as_int(dis[s] * dis[d]));
    }
}

// ---------------- weight prep: all 6 fp16 fragment planes + cvec, 1 launch --
__global__ __launch_bounds__(256) void wprep_kernel(
    const float* __restrict__ gcn1_W, const float* __restrict__ gcn2_W,
    const float* __restrict__ dnn_W1, const float* __restrict__ dnn_W2,
    const float* __restrict__ pred_W1,
    const float* __restrict__ cb, const float* __restrict__ cw,
    _Float16* __restrict__ G1f, _Float16* __restrict__ G2f,
    _Float16* __restrict__ W1f, _Float16* __restrict__ W2f,
    _Float16* __restrict__ Paf, _Float16* __restrict__ Pbf,
    float* __restrict__ cvec)
{
    int b = blockIdx.x;
    if (b == 704) {
        int col = threadIdx.x;
        if (col < 176) {
            float s = 0.f;
            if (col < 172)
                for (int k = 0; k < 172; ++k)
                    s += (cb[k] + cb[172 + k]) * pred_W1[(size_t)(172 + k) * 172 + col];
            cvec[col] = s;
        } else if (col == 176) {
            float c = 0.f;
            for (int k = 0; k < 172; ++k) c += cb[k] * cw[172 + k];
            cvec[176] = c;
        }
        return;
    }
    const float* W; _Float16* Wf; int K, Ncol, NT, base;
    if (b < 64)       { W = gcn1_W; Wf = G1f; K = 128; Ncol = 128; NT = 8;  base = 0;   }
    else if (b < 128) { W = gcn2_W; Wf = G2f; K = 128; Ncol = 128; NT = 8;  base = 64;  }
    else if (b < 272) { W = dnn_W1; Wf = W1f; K = 172; Ncol = 172; NT = 12; base = 128; }
    else if (b < 416) { W = dnn_W2; Wf = W2f; K = 172; Ncol = 172; NT = 12; base = 272; }
    else if (b < 560) { W = pred_W1; Wf = Paf; K = 172; Ncol = 172; NT = 12; base = 416; }
    else              { W = pred_W1 + (size_t)172 * 172; Wf = Pbf; K = 172; Ncol = 172; NT = 12; base = 560; }
    int idx = (b - base) * 256 + threadIdx.x;
    int e = idx & 7;
    int lane = (idx >> 3) & 63;
    int ct = idx >> 9;
    int t = ct % NT, c = ct / NT;
    int col = t * 16 + (lane & 15);
    int k = c * 32 + (lane >> 4) * 8 + e;
    float x = (k < K && col < Ncol) ? W[(size_t)k * Ncol + col] : 0.f;
    Wf[idx] = (_Float16)x;
}

// ---------------- g0: embed -> [N,44]@[44,128]+b, leaky -> sh f16 ---------
__global__ __launch_bounds__(256) void g0_kernel(
    const int* __restrict__ disc, const float* __restrict__ cont,
    const float* __restrict__ Wc, const float* __restrict__ bc,
    const float* __restrict__ W, const float* __restrict__ bias,
    _Float16* __restrict__ sh, int N)
{
    constexpr int TM = 32, K = 44, RB = 8;
    __shared__ float Alds[TM][K];
    __shared__ float Wlds[K][128];
    const int tid = threadIdx.x, lane = tid & 63, wv = tid >> 6;
    const int row0 = blockIdx.x * TM;

    for (int idx = tid; idx < TM * 38; idx += 256) {
        int r = idx / 38, j = idx - r * 38;
        int row = row0 + r;
        if (j == 0) {
            float o = 0.f;
            if (row < N) {
                const int* dr = disc + (size_t)row * 38;
                int best = dr[0], bi = 0;
                #pragma unroll
                for (int q = 1; q < 7; ++q) { int v = dr[q]; if (v > best) { best = v; bi = q; } }
                o = (float)bi;
            }
            Alds[r][0] = o;
        } else if (j >= 7) {
            Alds[r][j - 6] = (row < N) ? (float)disc[(size_t)row * 38 + j] : 0.f;
        }
    }
    for (int idx = tid; idx < TM * 12; idx += 256) {
        int r = idx / 12, q = idx - r * 12;
        int t = q >> 2, ch = q & 3;
        int row = row0 + r;
        float s = 0.f;
        if (row < N) {
            s = bc[ch];
            const float* cr = cont + (size_t)row * 90 + t * 30;
            #pragma unroll
            for (int j = 0; j < 30; ++j) s += cr[j] * Wc[j * 4 + ch];
        }
        Alds[r][32 + t * 4 + ch] = s;
    }
    for (int idx = tid; idx < K * 32; idx += 256) {
        int k = idx >> 5, c4 = idx & 31;
        ((float4*)&Wlds[k][0])[c4] = ((const float4*)W)[idx];
    }
    __syncthreads();

    float acc[RB][2];
    float b0 = bias[lane], b1 = bias[lane + 64];
    #pragma unroll
    for (int r = 0; r < RB; ++r) { acc[r][0] = b0; acc[r][1] = b1; }

    for (int k = 0; k < K; ++k) {
        float w0 = Wlds[k][lane], w1 = Wlds[k][lane + 64];
        #pragma unroll
        for (int r = 0; r < RB; ++r) {
            float a = Alds[wv * RB + r][k];
            acc[r][0] += a * w0;
            acc[r][1] += a * w1;
        }
    }
    #pragma unroll
    for (int r = 0; r < RB; ++r) {
        int row = row0 + wv * RB + r;
        if (row < N) {
            sh[(size_t)row * 128 + lane]      = (_Float16)leakyf(acc[r][0]);
            sh[(size_t)row * 128 + lane + 64] = (_Float16)leakyf(acc[r][1]);
        }
    }
}

// ---------------- fused GCN layer: shout = leaky(AGG(shin) @ G + b) --------
__global__ __launch_bounds__(512, 4) void gcn_fused(
    const _Float16* __restrict__ shin, const int2* __restrict__ colcf,
    const int* __restrict__ rowp, const int* __restrict__ rend,
    const float* __restrict__ dis, const _Float16* __restrict__ B,
    const float* __restrict__ bias, _Float16* __restrict__ shout, int N)
{
    __shared__ __attribute__((aligned(16))) _Float16 Xs[64][136];
    const int tid = threadIdx.x, lane = tid & 63, wv = tid >> 6;
    const int l15 = lane & 15, kq = lane >> 4;
    const int row0 = blockIdx.x * 64;
    const f16x2* S2 = (const f16x2*)shin;

    // ---- phase 1: gather + self-loop (f16 rows), int64 sum
    #pragma unroll 1
    for (int rr = 0; rr < 8; ++rr) {
        const int r = (wv << 3) + rr;
        const int row = row0 + r;
        float ox = 0.f, oy = 0.f;
        if (row < N) {
            int i = rowp[row], en = rend[row];
            long long iax = 0, iay = 0;
            for (; i + 7 < en; i += 8) {
                int2 ee[8];
                f16x2 vv[8];
                #pragma unroll
                for (int u = 0; u < 8; ++u) ee[u] = colcf[i + u];
                #pragma unroll
                for (int u = 0; u < 8; ++u) vv[u] = S2[(size_t)ee[u].x * 64 + lane];
                #pragma unroll
                for (int u = 0; u < 8; ++u) {
                    float cf = __int_as_float(ee[u].y) * AGG_SCALE;
                    iax += __float2int_rn((float)vv[u].x * cf);
                    iay += __float2int_rn((float)vv[u].y * cf);
                }
            }
            for (; i < en; ++i) {
                int2 e = colcf[i];
                f16x2 v = S2[(size_t)e.x * 64 + lane];
                float cf = __int_as_float(e.y) * AGG_SCALE;
                iax += __float2int_rn((float)v.x * cf);
                iay += __float2int_rn((float)v.y * cf);
            }
            float ax = (float)iax * AGG_INV;
            float ay = (float)iay * AGG_INV;
            float dn = dis[row];
            f16x2 sv = S2[(size_t)row * 64 + lane];
            float d2 = dn * dn;
            ox = ax + (float)sv.x * d2;
            oy = ay + (float)sv.y * d2;
        }
        f16x2 h = { (_Float16)ox, (_Float16)oy };
        *(f16x2*)&Xs[r][lane * 2] = h;
    }
    __syncthreads();

    // ---- phase 2: GEMM (wave = msub x half; 4 col-tiles per wave)
    const int msub = wv >> 1, half = wv & 1;
    f32x4 acc[4];
    #pragma unroll
    for (int t = 0; t < 4; ++t) acc[t] = (f32x4){0.f, 0.f, 0.f, 0.f};

    #pragma unroll
    for (int c = 0; c < 4; ++c) {
        f16x8 a = *(const f16x8*)&Xs[msub * 16 + l15][c * 32 + kq * 8];
        #pragma unroll
        for (int t = 0; t < 4; ++t) {
            int tg = half * 4 + t;
            f16x8 b = *(const f16x8*)(B + (((size_t)c * 8 + tg) * 64 + lane) * 8);
            acc[t] = MFMA16(a, b, acc[t]);
        }
    }

    #pragma unroll
    for (int t = 0; t < 4; ++t) {
        int col = (half * 4 + t) * 16 + l15;
        float bb = bias[col];
        #pragma unroll
        for (int r = 0; r < 4; ++r) {
            int row = row0 + msub * 16 + kq * 4 + r;
            if (row < N)
                shout[(size_t)row * 128 + col] = (_Float16)leakyf(acc[t][r] + bb);
        }
    }
}

// one pass, B-reuse layout: wave = (mp in {0,1}) x (qg in 0..3);
// wave handles rows mp*32..mp*32+31 (2 subtiles) x col-tiles {3qg,3qg+1,3qg+2};
// each B-fragment loaded once, used for 2 MFMAs. acc[sub][t] chunk order
// identical to the old per-accumulator order -> bit-identical results.
__device__ __forceinline__ void gemm_pass6(
    const _Float16 (*X)[200], const _Float16* __restrict__ B,
    f32x4 (*acc)[3], int mp, int qg, int l15, int kq, int lane)
{
    #pragma unroll
    for (int s = 0; s < 2; ++s)
        #pragma unroll
        for (int t = 0; t < 3; ++t) acc[s][t] = (f32x4){0.f, 0.f, 0.f, 0.f};
    #pragma unroll
    for (int c = 0; c < 6; ++c) {
        f16x8 a0 = *(const f16x8*)&X[mp * 32 + l15][c * 32 + kq * 8];
        f16x8 a1 = *(const f16x8*)&X[mp * 32 + 16 + l15][c * 32 + kq * 8];
        #pragma unroll
        for (int t = 0; t < 3; ++t) {
            f16x8 b = *(const f16x8*)(B + (((size_t)c * 12 + qg * 3 + t) * 64 + lane) * 8);
            acc[0][t] = MFMA16(a0, b, acc[0][t]);
            acc[1][t] = MFMA16(a1, b, acc[1][t]);
        }
    }
}

// ---------------- fused tail: dnn1+dnn2+pred1(a,b)+cross+pred2+sigmoid ----
__global__ __launch_bounds__(512, 3) void tail_kernel(
    const int* __restrict__ disc, const float* __restrict__ cont,
    const float* __restrict__ Wc, const float* __restrict__ bc,
    const _Float16* __restrict__ sh,
    const _Float16* __restrict__ W1, const float* __restrict__ b1,
    const _Float16* __restrict__ W2, const float* __restrict__ b2,
    const _Float16* __restrict__ Pa, const _Float16* __restrict__ Pb,
    const float* __restrict__ pb1,
    const float* __restrict__ cw, const float* __restrict__ cvec,
    const float* __restrict__ pw2, const float* __restrict__ pb2,
    float* __restrict__ out, int N)
{
    __shared__ __attribute__((aligned(16))) _Float16 Xs[64][200];
    __shared__ __attribute__((aligned(16))) _Float16 Ts[64][200];
    __shared__ float als[64];
    __shared__ float partial[64][4];
    const int tid = threadIdx.x, lane = tid & 63, wv = tid >> 6;
    const int mp = wv >> 2, qg = wv & 3, l15 = lane & 15, kq = lane >> 4;
    const int row0 = blockIdx.x * 64;

    // ---- phase A: coalesced cont tile -> Ts-as-f32 [64][100]
    float* TsF = (float*)&Ts[0][0];
    for (int idx = tid; idx < 64 * 45; idx += 512) {
        int r = idx / 45, j2 = idx - r * 45;
        int row = row0 + r;
        float2 v = make_float2(0.f, 0.f);
        if (row < N) v = ((const float2*)(cont + (size_t)row * 90))[j2];
        TsF[r * 100 + j2 * 2]     = v.x;
        TsF[r * 100 + j2 * 2 + 1] = v.y;
    }
    __syncthreads();

    // ---- phase B: embed from LDS (same f32 order) + xg shadow copy
    for (int idx = tid; idx < 64 * 44; idx += 512) {
        int r = idx / 44, j = idx - r * 44;
        int row = row0 + r;
        float v = 0.f;
        if (row < N) {
            if (j == 0) {
                const int* dr = disc + (size_t)row * 38;
                int best = dr[0], bi = 0;
                #pragma unroll
                for (int q = 1; q < 7; ++q) { int t = dr[q]; if (t > best) { best = t; bi = q; } }
                v = (float)bi;
            } else if (j < 32) {
                v = (float)disc[(size_t)row * 38 + j + 6];
            } else {
                int q = j - 32, t = q >> 2, ch = q & 3;
                float s = bc[ch];
                const float* crl = &TsF[r * 100 + t * 30];
                #pragma unroll
                for (int kk = 0; kk < 30; ++kk) s += crl[kk] * Wc[kk * 4 + ch];
                v = s;
            }
        }
        Xs[r][j] = (_Float16)v;
    }
    for (int idx = tid; idx < 64 * 32; idx += 512) {   // sh: 128 f16 = 32 x 8B
        int r = idx >> 5, q = idx & 31;
        int row = row0 + r;
        uint2 v = {0u, 0u};
        if (row < N) v = *(const uint2*)(sh + (size_t)row * 128 + q * 4);
        *(uint2*)&Xs[r][44 + q * 4] = v;
    }
    for (int idx = tid; idx < 64 * 28; idx += 512) {
        int r = idx / 28, j = idx - r * 28;
        Xs[r][172 + j] = (_Float16)0.f;
    }
    __syncthreads();

    // per-row cross scalars: xl2 = als*x0 + (b1c+b2c)
    {
        int row = tid >> 3, sub = tid & 7;
        float d1 = 0.f, d2 = 0.f;
        for (int col = sub; col < 172; col += 8) {
            float x = (float)Xs[row][col];
            d1 += x * cw[col];
            d2 += x * cw[172 + col];
        }
        #pragma unroll
        for (int off = 1; off < 8; off <<= 1) {
            d1 += __shfl_xor(d1, off, 64);
            d2 += __shfl_xor(d2, off, 64);
        }
        if (sub == 0) {
            float a1 = 1.f + d1;
            als[row] = a1 + a1 * d2 + cvec[176];
        }
    }

    f32x4 accA[2][3], accB[2][3];

    // dnn1: Xs -> Ts
    gemm_pass6(Xs, W1, accA, mp, qg, l15, kq, lane);
    #pragma unroll
    for (int s = 0; s < 2; ++s) {
        #pragma unroll
        for (int t = 0; t < 3; ++t) {
            int col = (qg * 3 + t) * 16 + l15;
            #pragma unroll
            for (int r = 0; r < 4; ++r) {
                int row = mp * 32 + s * 16 + kq * 4 + r;
                float v = (col < 172) ? leakyf(accA[s][t][r] + b1[col]) : 0.f;
                Ts[row][col] = (_Float16)v;
            }
        }
    }
    __syncthreads();
    // dnn2: Ts -> Ts (in place)
    gemm_pass6(Ts, W2, accA, mp, qg, l15, kq, lane);
    __syncthreads();
    #pragma unroll
    for (int s = 0; s < 2; ++s) {
        #pragma unroll
        for (int t = 0; t < 3; ++t) {
            int col = (qg * 3 + t) * 16 + l15;
            #pragma unroll
            for (int r = 0; r < 4; ++r) {
                int row = mp * 32 + s * 16 + kq * 4 + r;
                float v = (col < 172) ? leakyf(accA[s][t][r] + b2[col]) : 0.f;
                Ts[row][col] = (_Float16)v;
            }
        }
    }
    __syncthreads();

    // pred1: accA = xdeep@Pa (from Ts), accB = x0@Pb (from Xs)
    gemm_pass6(Ts, Pa, accA, mp, qg, l15, kq, lane);
    gemm_pass6(Xs, Pb, accB, mp, qg, l15, kq, lane);

    // epilogue: pre = accA + pb1 + als*accB + cvec -> leaky -> . pw2 -> sigmoid
    float part[2][4];
    #pragma unroll
    for (int s = 0; s < 2; ++s)
        #pragma unroll
        for (int r = 0; r < 4; ++r) part[s][r] = 0.f;
    #pragma unroll
    for (int s = 0; s < 2; ++s) {
        #pragma unroll
        for (int t = 0; t < 3; ++t) {
            int col = (qg * 3 + t) * 16 + l15;
            if (col < 172) {
                float cv = cvec[col] + pb1[col], w2v = pw2[col];
                #pragma unroll
                for (int r = 0; r < 4; ++r) {
                    int row = mp * 32 + s * 16 + kq * 4 + r;
                    float pre = accA[s][t][r] + als[row] * accB[s][t][r] + cv;
                    part[s][r] += leakyf(pre) * w2v;
                }
            }
        }
    }
    #pragma unroll
    for (int s = 0; s < 2; ++s)
        #pragma unroll
        for (int r = 0; r < 4; ++r) {
            #pragma unroll
            for (int off = 1; off < 16; off <<= 1)
                part[s][r] += __shfl_xor(part[s][r], off, 64);
        }
    if (l15 == 0) {
        #pragma unroll
        for (int s = 0; s < 2; ++s)
            #pragma unroll
            for (int r = 0; r < 4; ++r)
                partial[mp * 32 + s * 16 + kq * 4 + r][qg] = part[s][r];
    }
    __syncthreads();
    if (tid < 64) {
        int grow = row0 + tid;
        if (grow < N) {
            float ssum = partial[tid][0] + partial[tid][1]
                       + partial[tid][2] + partial[tid][3] + pb2[0];
            out[grow] = 1.f / (1.f + expf(-ssum));
        }
    }
}

extern "C" void kernel_launch(void* const* d_in, const int* in_sizes, int n_in,
                              void* d_out, int out_size, void* d_ws, size_t ws_size,
                              hipStream_t stream)
{
    const int*   disc    = (const int*)d_in[0];
    const float* cont    = (const float*)d_in[1];
    const int*   eidx    = (const int*)d_in[2];
    const float* emb_W   = (const float*)d_in[5];
    const float* emb_b   = (const float*)d_in[6];
    const float* g0_W    = (const float*)d_in[7];
    const float* g0_b    = (const float*)d_in[8];
    const float* gcn1_W  = (const float*)d_in[9];
    const float* gcn1_b  = (const float*)d_in[10];
    const float* gcn2_W  = (const float*)d_in[11];
    const float* gcn2_b  = (const float*)d_in[12];
    const float* dnn_W1  = (const float*)d_in[13];
    const float* dnn_b1  = (const float*)d_in[14];
    const float* dnn_W2  = (const float*)d_in[15];
    const float* dnn_b2  = (const float*)d_in[16];
    const float* cross_w = (const float*)d_in[17];
    const float* cross_b = (const float*)d_in[18];
    const float* pred_W1 = (const float*)d_in[19];
    const float* pred_b1 = (const float*)d_in[20];
    const float* pred_W2 = (const float*)d_in[21];
    const float* pred_b2 = (const float*)d_in[22];

    const int N = in_sizes[0] / 38;
    const int E = in_sizes[2] / 2;
    const int* src = eidx;
    const int* dst = eidx + E;

    // ---- workspace (~66 MB) ----
    _Float16* shA = (_Float16*)d_ws;                      // [N,128] f16
    _Float16* shB = shA + (size_t)128 * N;                // [N,128] f16
    float* dis  = (float*)(shB + (size_t)128 * N);        // [N]
    int* cnt    = (int*)(dis + N);                        // [N]
    int* rowp   = cnt + N;                                // [N]
    int* curs   = rowp + N;                               // [N]
    int* bsum   = curs + N;                               // [512]
    int2* colcf = (int2*)(((size_t)(bsum + 512) + 15) & ~(size_t)15);  // [E]
    _Float16* wf = (_Float16*)(colcf + E);
    _Float16* G1f = wf;              // 4*8*512   = 16384
    _Float16* G2f = G1f + 16384;
    _Float16* W1f = G2f + 16384;     // 6*12*512  = 36864
    _Float16* W2f = W1f + 36864;
    _Float16* Paf = W2f + 36864;
    _Float16* Pbf = Paf + 36864;
    float* cvec   = (float*)(Pbf + 36864);                // [192]

    auto cdiv = [](int a, int b) { return (a + b - 1) / b; };
    const int nb = cdiv(N, 256);

    // weight prep: all planes + cvec in ONE launch
    wprep_kernel<<<705, 256, 0, stream>>>(
        gcn1_W, gcn2_W, dnn_W1, dnn_W2, pred_W1, cross_b, cross_w,
        G1f, G2f, W1f, W2f, Paf, Pbf, cvec);

    // CSR build (+ per-edge coeff)
    hipMemsetAsync(cnt, 0, (size_t)N * sizeof(int), stream);
    cnt_edge_kernel<<<cdiv(E, 256), 256, 0, stream>>>(dst, cnt, E);
    scan1_kernel<<<nb, 256, 0, stream>>>(cnt, curs, bsum, N);
    scan2_kernel<<<1, 64, 0, stream>>>(bsum, nb);
    scan3_kernel<<<nb, 256, 0, stream>>>(curs, cnt, bsum, rowp, curs, dis, N);
    fill_kernel<<<cdiv(E, 256), 256, 0, stream>>>(src, dst, dis, curs, colcf, E);

    // g0 -> shA (f16)
    g0_kernel<<<cdiv(N, 32), 256, 0, stream>>>(disc, cont, emb_W, emb_b, g0_W, g0_b,
                                               shA, N);

    // GCN L1: shA -> shB ; GCN L2: shB -> shA
    gcn_fused<<<cdiv(N, 64), 512, 0, stream>>>(shA, colcf, rowp, curs, dis,
                                               G1f, gcn1_b, shB, N);
    gcn_fused<<<cdiv(N, 64), 512, 0, stream>>>(shB, colcf, rowp, curs, dis,
                                               G2f, gcn2_b, shA, N);

    // fused tail -> out
    tail_kernel<<<cdiv(N, 64), 512, 0, stream>>>(
        disc, cont, emb_W, emb_b, shA,
        W1f, dnn_b1, W2f, dnn_b2, Paf, Pbf, pred_b1,
        cross_w, cvec, pred_W2, pred_b2, (float*)d_out, N);
}